// Round 1
// baseline (355.392 us; speedup 1.0000x reference)
//
#include <hip/hip_runtime.h>

#define T_TOK 16384
#define C_DIM 1024

typedef float f32x4 __attribute__((ext_vector_type(4)));
typedef __bf16 bf16x8 __attribute__((ext_vector_type(8)));
typedef unsigned short u16x8 __attribute__((ext_vector_type(8)));
typedef unsigned short u16x4 __attribute__((ext_vector_type(4)));

__device__ __forceinline__ unsigned short f2bf(float f) {
  union { float f; unsigned u; } v; v.f = f;
  unsigned r = v.u + 0x7fffu + ((v.u >> 16) & 1u);
  return (unsigned short)(r >> 16);
}
__device__ __forceinline__ float bf2f(unsigned short h) {
  union { unsigned u; float f; } v; v.u = ((unsigned)h) << 16;
  return v.f;
}

// ---------------- f32 -> bf16 weight conversion ----------------
__global__ __launch_bounds__(256) void cvt_kernel(const float* __restrict__ in,
                                                  unsigned short* __restrict__ out, int n4) {
  int i = blockIdx.x * 256 + threadIdx.x;
  if (i >= n4) return;
  f32x4 v = *(const f32x4*)(in + (size_t)i * 4);
  u16x4 o;
#pragma unroll
  for (int j = 0; j < 4; ++j) o[j] = f2bf(v[j]);
  *(u16x4*)(out + (size_t)i * 4) = o;
}

// ---------------- LayerNorm stats: mean/rstd per token ----------------
__global__ __launch_bounds__(256) void ln_stats_kernel(const float* __restrict__ x,
                                                       float* __restrict__ mu,
                                                       float* __restrict__ rstd) {
  __shared__ float s1[4][64];
  __shared__ float s2[4][64];
  const int tid = threadIdx.x;
  const int lt = tid & 63, cq = tid >> 6;
  const int t = blockIdx.x * 64 + lt;
  float s = 0.f, ss = 0.f;
  const float* p = x + (size_t)cq * 256 * T_TOK + t;
  for (int c = 0; c < 256; ++c) {
    float v = p[(size_t)c * T_TOK];
    s += v; ss += v * v;
  }
  s1[cq][lt] = s; s2[cq][lt] = ss;
  __syncthreads();
  if (tid < 64) {
    float S  = s1[0][tid] + s1[1][tid] + s1[2][tid] + s1[3][tid];
    float SS = s2[0][tid] + s2[1][tid] + s2[2][tid] + s2[3][tid];
    float m = S * (1.f / 1024.f);
    float var = SS * (1.f / 1024.f) - m * m;
    mu[blockIdx.x * 64 + tid] = m;
    rstd[blockIdx.x * 64 + tid] = rsqrtf(var + 1e-5f);
  }
}

// ---------------- LN apply + transpose: x (C,T) -> normed (T,C) bf16 ----------------
__global__ __launch_bounds__(256) void ln_tr_kernel(const float* __restrict__ x,
                                                    const float* __restrict__ mu,
                                                    const float* __restrict__ rstd,
                                                    const float* __restrict__ gamma,
                                                    const float* __restrict__ beta,
                                                    unsigned short* __restrict__ normed) {
  __shared__ float tile[64][65];
  __shared__ float gs[64], bs[64], ms[64], rs[64];
  const int tid = threadIdx.x;
  const int bt = blockIdx.x & 255;   // 256 token tiles of 64
  const int bc = blockIdx.x >> 8;    // 16 channel tiles of 64
  const int t0 = bt * 64, c0 = bc * 64;
  if (tid < 64) {
    gs[tid] = gamma[c0 + tid];
    bs[tid] = beta[c0 + tid];
    ms[tid] = mu[t0 + tid];
    rs[tid] = rstd[t0 + tid];
  }
  const int lc = tid >> 4;
  const int lt4 = (tid & 15) * 4;
#pragma unroll
  for (int r = 0; r < 4; ++r) {
    int c = r * 16 + lc;
    f32x4 v = *(const f32x4*)&x[(size_t)(c0 + c) * T_TOK + t0 + lt4];
    tile[c][lt4 + 0] = v[0]; tile[c][lt4 + 1] = v[1];
    tile[c][lt4 + 2] = v[2]; tile[c][lt4 + 3] = v[3];
  }
  __syncthreads();
#pragma unroll
  for (int r = 0; r < 2; ++r) {
    int idx = r * 256 + tid;
    int t = idx >> 3;
    int c8 = (idx & 7) * 8;
    float m = ms[t], rr = rs[t];
    u16x8 o;
#pragma unroll
    for (int j = 0; j < 8; ++j) {
      float v = tile[c8 + j][t];
      v = (v - m) * rr * gs[c8 + j] + bs[c8 + j];
      o[j] = f2bf(v);
    }
    *(u16x8*)&normed[(size_t)(t0 + t) * C_DIM + c0 + c8] = o;
  }
}

// ---------------- bf16 NT GEMM, 128x128 tile, BK=32, m97 structure ----------------
// A: M x K row-major bf16; B: N x K row-major bf16 (i.e. C = A * B^T)
// EPI 0: write bf16 to Obf (ld = ldo).  EPI 1: Ofp[col*T + row] = acc + Xadd[col*T + row].
#define GLDS(gp, lp) \
  __builtin_amdgcn_global_load_lds((const __attribute__((address_space(1))) void*)(gp), \
                                   (__attribute__((address_space(3))) void*)(lp), 16, 0, 0)

template <int EPI>
__global__ __launch_bounds__(256) void gemm_kernel(const unsigned short* __restrict__ A,
                                                   const unsigned short* __restrict__ B,
                                                   unsigned short* __restrict__ Obf, int ldo,
                                                   const float* __restrict__ Xadd,
                                                   float* __restrict__ Ofp,
                                                   int M, int N, int K) {
  __shared__ unsigned short Al[2][128 * 32];
  __shared__ unsigned short Bl[2][128 * 32];
  const int tid = threadIdx.x;
  const int wid = tid >> 6, lane = tid & 63;
  const int nbm = M >> 7;
  const int mt = blockIdx.x % nbm;
  const int nt = blockIdx.x / nbm;
  const size_t m0 = (size_t)mt * 128, n0 = (size_t)nt * 128;
  const int wr = wid >> 1, wc = wid & 1;

  // staging: chunk ch = wid*2 + {0,1}; lane i covers row ch*16 + i/4, k-half (i%4)*8
  const int srow = lane >> 2;
  const int skh = (lane & 3) * 8;
  const int ch0 = wid * 2, ch1 = wid * 2 + 1;
  const unsigned short* a0 = A + (m0 + ch0 * 16 + srow) * (size_t)K + skh;
  const unsigned short* a1 = A + (m0 + ch1 * 16 + srow) * (size_t)K + skh;
  const unsigned short* b0 = B + (n0 + ch0 * 16 + srow) * (size_t)K + skh;
  const unsigned short* b1 = B + (n0 + ch1 * 16 + srow) * (size_t)K + skh;

  auto stage = [&](int buf, int k0) {
    GLDS(a0 + k0, &Al[buf][ch0 * 512]);
    GLDS(a1 + k0, &Al[buf][ch1 * 512]);
    GLDS(b0 + k0, &Bl[buf][ch0 * 512]);
    GLDS(b1 + k0, &Bl[buf][ch1 * 512]);
  };

  f32x4 acc[4][4];
#pragma unroll
  for (int i = 0; i < 4; ++i)
#pragma unroll
    for (int j = 0; j < 4; ++j) acc[i][j] = (f32x4){0.f, 0.f, 0.f, 0.f};

  const int KS = K >> 5;
  const int arow = wr * 64 + (lane & 15);
  const int brow = wc * 64 + (lane & 15);
  const int koff = (lane >> 4) * 8;

  stage(0, 0);
  int buf = 0;
  for (int ks = 0; ks < KS; ++ks) {
    __syncthreads();  // staging into buf complete (vmcnt drain), prev reads done
    if (ks + 1 < KS) stage(buf ^ 1, (ks + 1) * 32);
    bf16x8 af[4], bfr[4];
#pragma unroll
    for (int mi = 0; mi < 4; ++mi)
      af[mi] = *(const bf16x8*)&Al[buf][(arow + mi * 16) * 32 + koff];
#pragma unroll
    for (int ni = 0; ni < 4; ++ni)
      bfr[ni] = *(const bf16x8*)&Bl[buf][(brow + ni * 16) * 32 + koff];
#pragma unroll
    for (int mi = 0; mi < 4; ++mi)
#pragma unroll
      for (int ni = 0; ni < 4; ++ni)
        acc[mi][ni] = __builtin_amdgcn_mfma_f32_16x16x32_bf16(af[mi], bfr[ni], acc[mi][ni], 0, 0, 0);
    buf ^= 1;
  }

  // epilogue: C/D layout col = lane&15, row = (lane>>4)*4 + reg  [m89-verified]
  const int r0 = wr * 64 + (lane >> 4) * 4;
  const int ccol = wc * 64 + (lane & 15);
  if (EPI == 0) {
#pragma unroll
    for (int mi = 0; mi < 4; ++mi) {
      size_t trow = m0 + r0 + mi * 16;
#pragma unroll
      for (int ni = 0; ni < 4; ++ni) {
        size_t col = n0 + ccol + ni * 16;
#pragma unroll
        for (int r = 0; r < 4; ++r)
          Obf[(trow + r) * (size_t)ldo + col] = f2bf(acc[mi][ni][r]);
      }
    }
  } else {
#pragma unroll
    for (int mi = 0; mi < 4; ++mi) {
      size_t trow = m0 + r0 + mi * 16;
#pragma unroll
      for (int ni = 0; ni < 4; ++ni) {
        size_t col = n0 + ccol + ni * 16;
        f32x4 xv = *(const f32x4*)&Xadd[col * T_TOK + trow];
        f32x4 o = acc[mi][ni] + xv;
        *(f32x4*)&Ofp[col * T_TOK + trow] = o;
      }
    }
  }
}

// ---------------- windowed attention with RoPE ----------------
// one block per (window, head); qkv: (T, 3072) bf16; aout: (T, 1024) bf16
__global__ __launch_bounds__(256) void attn_kernel(const unsigned short* __restrict__ qkv,
                                                   unsigned short* __restrict__ aout) {
  __shared__ float Qs[32][68], Ks[32][68], Vs[32][68];
  __shared__ float P[32][36];
  const int tid = threadIdx.x;
  const int w = blockIdx.x >> 4;
  const int h = blockIdx.x & 15;
  const int n = tid >> 3;
  const int d8 = (tid & 7) * 8;
  const size_t base = ((size_t)(w * 32 + n)) * 3072 + h * 64 + d8;
  u16x8 qv = *(const u16x8*)&qkv[base];
  u16x8 kv = *(const u16x8*)&qkv[base + 1024];
  u16x8 vv = *(const u16x8*)&qkv[base + 2048];
#pragma unroll
  for (int j = 0; j < 8; ++j) {
    Qs[n][d8 + j] = bf2f(qv[j]);
    Ks[n][d8 + j] = bf2f(kv[j]);
    Vs[n][d8 + j] = bf2f(vv[j]);
  }
  __syncthreads();
  // RoPE (window-local position n): angle = n * 10000^(-(d%32)/32)
  float qn[8], kn[8];
#pragma unroll
  for (int j = 0; j < 8; ++j) {
    int d = d8 + j;
    int i = d & 31;
    float ang = (float)n * __powf(10000.f, -(float)i * (1.f / 32.f));
    float cs = cosf(ang), sn = sinf(ang);
    float rq, rk;
    if (d < 32) { rq = -Qs[n][d + 32]; rk = -Ks[n][d + 32]; }
    else        { rq =  Qs[n][d - 32]; rk =  Ks[n][d - 32]; }
    qn[j] = Qs[n][d] * cs + rq * sn;
    kn[j] = Ks[n][d] * cs + rk * sn;
  }
  __syncthreads();
#pragma unroll
  for (int j = 0; j < 8; ++j) { Qs[n][d8 + j] = qn[j]; Ks[n][d8 + j] = kn[j]; }
  __syncthreads();
  // logits: each thread computes (nq, 4 keys)
  {
    const int nq = tid >> 3;
    const int mq = (tid & 7) * 4;
    f32x4 accv = {0.f, 0.f, 0.f, 0.f};
    for (int d = 0; d < 64; d += 4) {
      f32x4 qd = *(const f32x4*)&Qs[nq][d];
#pragma unroll
      for (int mm = 0; mm < 4; ++mm) {
        f32x4 kd = *(const f32x4*)&Ks[mq + mm][d];
        accv[mm] += qd[0] * kd[0] + qd[1] * kd[1] + qd[2] * kd[2] + qd[3] * kd[3];
      }
    }
#pragma unroll
    for (int mm = 0; mm < 4; ++mm) P[nq][mq + mm] = accv[mm] * 0.125f;
  }
  __syncthreads();
  if (tid < 32) {
    float mx = -1e30f;
    for (int m = 0; m < 32; ++m) mx = fmaxf(mx, P[tid][m]);
    float s = 0.f;
    for (int m = 0; m < 32; ++m) { float e = __expf(P[tid][m] - mx); P[tid][m] = e; s += e; }
    float inv = 1.f / s;
    for (int m = 0; m < 32; ++m) P[tid][m] *= inv;
  }
  __syncthreads();
  // PV: thread owns (n, d8..d8+7)
  {
    f32x4 o0 = {0.f, 0.f, 0.f, 0.f}, o1 = {0.f, 0.f, 0.f, 0.f};
    for (int m = 0; m < 32; ++m) {
      float p = P[n][m];
      f32x4 v0 = *(const f32x4*)&Vs[m][d8];
      f32x4 v1 = *(const f32x4*)&Vs[m][d8 + 4];
      o0 += p * v0;
      o1 += p * v1;
    }
    u16x8 ov;
#pragma unroll
    for (int j = 0; j < 4; ++j) { ov[j] = f2bf(o0[j]); ov[4 + j] = f2bf(o1[j]); }
    *(u16x8*)&aout[((size_t)(w * 32 + n)) * 1024 + h * 64 + d8] = ov;
  }
}

extern "C" void kernel_launch(void* const* d_in, const int* in_sizes, int n_in,
                              void* d_out, int out_size, void* d_ws, size_t ws_size,
                              hipStream_t stream) {
  const float* x     = (const float*)d_in[0];
  const float* w_qkv = (const float*)d_in[1];
  const float* w_out = (const float*)d_in[2];
  const float* gamma = (const float*)d_in[3];
  const float* beta  = (const float*)d_in[4];

  char* ws = (char*)d_ws;
  unsigned short* wqkv_bf = (unsigned short*)(ws);                       // 6,291,456 B
  unsigned short* wout_bf = (unsigned short*)(ws + 6291456);             // 2,097,152 B
  float* mu   = (float*)(ws + 8388608);                                  // 65,536 B
  float* rstd = (float*)(ws + 8454144);                                  // 65,536 B
  unsigned short* normed = (unsigned short*)(ws + 8519680);              // 33,554,432 B
  unsigned short* qkv    = (unsigned short*)(ws + 42074112);             // 100,663,296 B
  unsigned short* aout   = normed;  // reuse: normed dead after GEMM1

  cvt_kernel<<<3072, 256, 0, stream>>>(w_qkv, wqkv_bf, 3072 * 1024 / 4);
  cvt_kernel<<<1024, 256, 0, stream>>>(w_out, wout_bf, 1024 * 1024 / 4);
  ln_stats_kernel<<<256, 256, 0, stream>>>(x, mu, rstd);
  ln_tr_kernel<<<4096, 256, 0, stream>>>(x, mu, rstd, gamma, beta, normed);
  gemm_kernel<0><<<128 * 24, 256, 0, stream>>>(normed, wqkv_bf, qkv, 3072,
                                               nullptr, nullptr, 16384, 3072, 1024);
  attn_kernel<<<8192, 256, 0, stream>>>(qkv, aout);
  gemm_kernel<1><<<128 * 8, 256, 0, stream>>>(aout, wout_bf, nullptr, 0,
                                              x, (float*)d_out, 16384, 1024, 1024);
}

// Round 2
// 281.642 us; speedup vs baseline: 1.2619x; 1.2619x over previous
//
#include <hip/hip_runtime.h>

#define T_TOK 16384
#define C_DIM 1024

typedef float f32x4 __attribute__((ext_vector_type(4)));
typedef float f32x16 __attribute__((ext_vector_type(16)));
typedef __bf16 bf16x8 __attribute__((ext_vector_type(8)));
typedef unsigned short u16x8 __attribute__((ext_vector_type(8)));
typedef unsigned short u16x4 __attribute__((ext_vector_type(4)));

__device__ __forceinline__ unsigned short f2bf(float f) {
  union { float f; unsigned u; } v; v.f = f;
  unsigned r = v.u + 0x7fffu + ((v.u >> 16) & 1u);
  return (unsigned short)(r >> 16);
}
__device__ __forceinline__ float bf2f(unsigned short h) {
  union { unsigned u; float f; } v; v.u = ((unsigned)h) << 16;
  return v.f;
}
__device__ __forceinline__ unsigned pk2(float a, float b) {
  return (unsigned)f2bf(a) | ((unsigned)f2bf(b) << 16);
}

// ---------------- f32 -> bf16 weight conversion ----------------
__global__ __launch_bounds__(256) void cvt_kernel(const float* __restrict__ in,
                                                  unsigned short* __restrict__ out, int n4) {
  int i = blockIdx.x * 256 + threadIdx.x;
  if (i >= n4) return;
  f32x4 v = *(const f32x4*)(in + (size_t)i * 4);
  u16x4 o;
#pragma unroll
  for (int j = 0; j < 4; ++j) o[j] = f2bf(v[j]);
  *(u16x4*)(out + (size_t)i * 4) = o;
}

// ---------------- RoPE table: [32 pos][32 dmod] float2 (cos,sin) ----------------
__global__ __launch_bounds__(256) void rope_tab_kernel(float* __restrict__ tab) {
  int idx = blockIdx.x * 256 + threadIdx.x;
  if (idx >= 1024) return;
  int mm = idx >> 5, d = idx & 31;
  float invf = powf(10000.f, -(float)d * (1.f / 32.f));
  float ang = (float)mm * invf;
  float s, c;
  sincosf(ang, &s, &c);
  tab[idx * 2] = c;
  tab[idx * 2 + 1] = s;
}

// ---------------- LayerNorm stats: mean/rstd per token ----------------
__global__ __launch_bounds__(256) void ln_stats_kernel(const float* __restrict__ x,
                                                       float* __restrict__ mu,
                                                       float* __restrict__ rstd) {
  __shared__ float s1[4][64];
  __shared__ float s2[4][64];
  const int tid = threadIdx.x;
  const int lt = tid & 63, cq = tid >> 6;
  const int t = blockIdx.x * 64 + lt;
  float s = 0.f, ss = 0.f;
  const float* p = x + (size_t)cq * 256 * T_TOK + t;
  for (int c = 0; c < 256; ++c) {
    float v = p[(size_t)c * T_TOK];
    s += v; ss += v * v;
  }
  s1[cq][lt] = s; s2[cq][lt] = ss;
  __syncthreads();
  if (tid < 64) {
    float S  = s1[0][tid] + s1[1][tid] + s1[2][tid] + s1[3][tid];
    float SS = s2[0][tid] + s2[1][tid] + s2[2][tid] + s2[3][tid];
    float m = S * (1.f / 1024.f);
    float var = SS * (1.f / 1024.f) - m * m;
    mu[blockIdx.x * 64 + tid] = m;
    rstd[blockIdx.x * 64 + tid] = rsqrtf(var + 1e-5f);
  }
}

// ---------------- LN apply + transpose: x (C,T) -> normed (T,C) bf16 ----------------
__global__ __launch_bounds__(256) void ln_tr_kernel(const float* __restrict__ x,
                                                    const float* __restrict__ mu,
                                                    const float* __restrict__ rstd,
                                                    const float* __restrict__ gamma,
                                                    const float* __restrict__ beta,
                                                    unsigned short* __restrict__ normed) {
  __shared__ float tile[64][65];
  __shared__ float gs[64], bs[64], ms[64], rs[64];
  const int tid = threadIdx.x;
  const int bt = blockIdx.x & 255;
  const int bc = blockIdx.x >> 8;
  const int t0 = bt * 64, c0 = bc * 64;
  if (tid < 64) {
    gs[tid] = gamma[c0 + tid];
    bs[tid] = beta[c0 + tid];
    ms[tid] = mu[t0 + tid];
    rs[tid] = rstd[t0 + tid];
  }
  const int lc = tid >> 4;
  const int lt4 = (tid & 15) * 4;
#pragma unroll
  for (int r = 0; r < 4; ++r) {
    int c = r * 16 + lc;
    f32x4 v = *(const f32x4*)&x[(size_t)(c0 + c) * T_TOK + t0 + lt4];
    tile[c][lt4 + 0] = v[0]; tile[c][lt4 + 1] = v[1];
    tile[c][lt4 + 2] = v[2]; tile[c][lt4 + 3] = v[3];
  }
  __syncthreads();
#pragma unroll
  for (int r = 0; r < 2; ++r) {
    int idx = r * 256 + tid;
    int t = idx >> 3;
    int c8 = (idx & 7) * 8;
    float m = ms[t], rr = rs[t];
    u16x8 o;
#pragma unroll
    for (int j = 0; j < 8; ++j) {
      float v = tile[c8 + j][t];
      v = (v - m) * rr * gs[c8 + j] + bs[c8 + j];
      o[j] = f2bf(v);
    }
    *(u16x8*)&normed[(size_t)(t0 + t) * C_DIM + c0 + c8] = o;
  }
}

// ---------------- bf16 NT GEMM, 128x128 tile, BK=32, m97 structure + XCD swizzle ----------------
#define GLDS(gp, lp) \
  __builtin_amdgcn_global_load_lds((const __attribute__((address_space(1))) void*)(gp), \
                                   (__attribute__((address_space(3))) void*)(lp), 16, 0, 0)

template <int EPI>
__global__ __launch_bounds__(256) void gemm_kernel(const unsigned short* __restrict__ A,
                                                   const unsigned short* __restrict__ B,
                                                   unsigned short* __restrict__ Obf, int ldo,
                                                   const float* __restrict__ Xadd,
                                                   float* __restrict__ Ofp,
                                                   int M, int N, int K) {
  __shared__ unsigned short Al[2][128 * 32];
  __shared__ unsigned short Bl[2][128 * 32];
  const int tid = threadIdx.x;
  const int wid = tid >> 6, lane = tid & 63;
  const int nbm = M >> 7;
  // bijective XCD swizzle (grid divisible by 8)
  const int nwg = gridDim.x;
  const int orig = blockIdx.x;
  const int wg = (orig & 7) * (nwg >> 3) + (orig >> 3);
  const int mt = wg % nbm;
  const int nt = wg / nbm;
  const size_t m0 = (size_t)mt * 128, n0 = (size_t)nt * 128;
  const int wr = wid >> 1, wc = wid & 1;

  const int srow = lane >> 2;
  const int skh = (lane & 3) * 8;
  const int ch0 = wid * 2, ch1 = wid * 2 + 1;
  const unsigned short* a0 = A + (m0 + ch0 * 16 + srow) * (size_t)K + skh;
  const unsigned short* a1 = A + (m0 + ch1 * 16 + srow) * (size_t)K + skh;
  const unsigned short* b0 = B + (n0 + ch0 * 16 + srow) * (size_t)K + skh;
  const unsigned short* b1 = B + (n0 + ch1 * 16 + srow) * (size_t)K + skh;

  auto stage = [&](int buf, int k0) {
    GLDS(a0 + k0, &Al[buf][ch0 * 512]);
    GLDS(a1 + k0, &Al[buf][ch1 * 512]);
    GLDS(b0 + k0, &Bl[buf][ch0 * 512]);
    GLDS(b1 + k0, &Bl[buf][ch1 * 512]);
  };

  f32x4 acc[4][4];
#pragma unroll
  for (int i = 0; i < 4; ++i)
#pragma unroll
    for (int j = 0; j < 4; ++j) acc[i][j] = (f32x4){0.f, 0.f, 0.f, 0.f};

  const int KS = K >> 5;
  const int arow = wr * 64 + (lane & 15);
  const int brow = wc * 64 + (lane & 15);
  const int koff = (lane >> 4) * 8;

  stage(0, 0);
  int buf = 0;
  for (int ks = 0; ks < KS; ++ks) {
    __syncthreads();
    if (ks + 1 < KS) stage(buf ^ 1, (ks + 1) * 32);
    bf16x8 af[4], bfr[4];
#pragma unroll
    for (int mi = 0; mi < 4; ++mi)
      af[mi] = *(const bf16x8*)&Al[buf][(arow + mi * 16) * 32 + koff];
#pragma unroll
    for (int ni = 0; ni < 4; ++ni)
      bfr[ni] = *(const bf16x8*)&Bl[buf][(brow + ni * 16) * 32 + koff];
#pragma unroll
    for (int mi = 0; mi < 4; ++mi)
#pragma unroll
      for (int ni = 0; ni < 4; ++ni)
        acc[mi][ni] = __builtin_amdgcn_mfma_f32_16x16x32_bf16(af[mi], bfr[ni], acc[mi][ni], 0, 0, 0);
    buf ^= 1;
  }

  const int r0 = wr * 64 + (lane >> 4) * 4;
  const int ccol = wc * 64 + (lane & 15);
  if (EPI == 0) {
#pragma unroll
    for (int mi = 0; mi < 4; ++mi) {
      size_t trow = m0 + r0 + mi * 16;
#pragma unroll
      for (int ni = 0; ni < 4; ++ni) {
        size_t col = n0 + ccol + ni * 16;
#pragma unroll
        for (int r = 0; r < 4; ++r)
          Obf[(trow + r) * (size_t)ldo + col] = f2bf(acc[mi][ni][r]);
      }
    }
  } else {
#pragma unroll
    for (int mi = 0; mi < 4; ++mi) {
      size_t trow = m0 + r0 + mi * 16;
#pragma unroll
      for (int ni = 0; ni < 4; ++ni) {
        size_t col = n0 + ccol + ni * 16;
        f32x4 xv = *(const f32x4*)&Xadd[col * T_TOK + trow];
        f32x4 o = acc[mi][ni] + xv;
        *(f32x4*)&Ofp[col * T_TOK + trow] = o;
      }
    }
  }
}

// ---------------- MFMA windowed attention with RoPE ----------------
// one wave per (window, head); 4 waves/block; no __syncthreads needed.
// S^T = mfma(Kfrag, Qfrag): lane holds col n = lane&31, rows m = (r&3)+8*(r>>2)+4*hi.
__global__ __launch_bounds__(256) void attn_kernel(const unsigned short* __restrict__ qkv,
                                                   const float* __restrict__ ropeT,
                                                   unsigned short* __restrict__ aout) {
  __shared__ unsigned short Vt[4][64][32];  // per-wave transposed V, chunk-XOR swizzled
  const int tid = threadIdx.x;
  const int wv = tid >> 6;
  const int lane = tid & 63;
  const int m = lane & 31;       // token row within window (for loads)
  const int hi = lane >> 5;
  const int gw = blockIdx.x * 4 + wv;
  const int w = gw >> 4, h = gw & 15;
  const size_t rowbase = ((size_t)(w * 32 + m)) * 3072 + (size_t)h * 64;
  const unsigned short* qp = qkv + rowbase;

  u16x8 qv[4], kv[4], vv[4];
#pragma unroll
  for (int s = 0; s < 4; ++s) {
    int off = s * 16 + hi * 8;
    qv[s] = *(const u16x8*)(qp + off);
    kv[s] = *(const u16x8*)(qp + 1024 + off);
    vv[s] = *(const u16x8*)(qp + 2048 + off);
  }

  // stage V transposed into LDS: Vt[d][slot(m)] = V[m][d], chunk-XOR swizzle
#pragma unroll
  for (int s = 0; s < 4; ++s)
#pragma unroll
    for (int j = 0; j < 8; ++j) {
      int d = s * 16 + hi * 8 + j;
      int slot = (((m >> 3) ^ (d ^ (d >> 2))) & 3) * 8 + (m & 7);
      Vt[wv][d][slot] = vv[s][j];
    }

  // rope table: lane needs float2(cos,sin) at [m][kp*16+hi*8+j], kp=ks&1
  f32x4 ct[2][4];
  const float* tp = ropeT + (size_t)(m * 32 + hi * 8) * 2;
#pragma unroll
  for (int kp = 0; kp < 2; ++kp)
#pragma unroll
    for (int q = 0; q < 4; ++q)
      ct[kp][q] = *(const f32x4*)(tp + kp * 32 + q * 4);

  union FU { unsigned u[4]; bf16x8 v; };
  // RoPE + pack rotated Q,K fragments (lane-local: d and d^32 are frags ks and ks^2)
  bf16x8 qfr[4], kfr[4];
#pragma unroll
  for (int ks = 0; ks < 4; ++ks) {
    const int kp = ks & 1;
    FU fq, fk;
#pragma unroll
    for (int jp = 0; jp < 4; ++jp) {
      float c0 = ct[kp][jp][0], s0 = ct[kp][jp][1];
      float c1 = ct[kp][jp][2], s1 = ct[kp][jp][3];
      float q0 = bf2f(qv[ks][2 * jp]), q1 = bf2f(qv[ks][2 * jp + 1]);
      float k0 = bf2f(kv[ks][2 * jp]), k1 = bf2f(kv[ks][2 * jp + 1]);
      float rq0, rq1, rk0, rk1;
      if (ks < 2) {
        rq0 = -bf2f(qv[ks + 2][2 * jp]); rq1 = -bf2f(qv[ks + 2][2 * jp + 1]);
        rk0 = -bf2f(kv[ks + 2][2 * jp]); rk1 = -bf2f(kv[ks + 2][2 * jp + 1]);
      } else {
        rq0 = bf2f(qv[ks - 2][2 * jp]); rq1 = bf2f(qv[ks - 2][2 * jp + 1]);
        rk0 = bf2f(kv[ks - 2][2 * jp]); rk1 = bf2f(kv[ks - 2][2 * jp + 1]);
      }
      fq.u[jp] = pk2(q0 * c0 + rq0 * s0, q1 * c1 + rq1 * s1);
      fk.u[jp] = pk2(k0 * c0 + rk0 * s0, k1 * c1 + rk1 * s1);
    }
    qfr[ks] = fq.v; kfr[ks] = fk.v;
  }

  f32x16 accS;
#pragma unroll
  for (int i = 0; i < 16; ++i) accS[i] = 0.f;
#pragma unroll
  for (int ks = 0; ks < 4; ++ks)
    accS = __builtin_amdgcn_mfma_f32_32x32x16_bf16(kfr[ks], qfr[ks], accS, 0, 0, 0);

  // softmax over m (rows): lane-local 16 + partner(lane^32) 16
  float p[16];
  float mx = -1e30f;
#pragma unroll
  for (int r = 0; r < 16; ++r) { p[r] = accS[r] * 0.125f; mx = fmaxf(mx, p[r]); }
  mx = fmaxf(mx, __shfl_xor(mx, 32, 64));
  float sum = 0.f;
#pragma unroll
  for (int r = 0; r < 16; ++r) { p[r] = __expf(p[r] - mx); sum += p[r]; }
  sum += __shfl_xor(sum, 32, 64);
  const float inv = 1.f / sum;
#pragma unroll
  for (int r = 0; r < 16; ++r) p[r] *= inv;

  // pack P into PV A-frags: lane l needs P[n=l&31][m = ks*16 + hi*8 + j]
  bf16x8 pfr[2];
  {
    FU f0, f1;
    unsigned a0 = hi ? pk2(p[0], p[1]) : pk2(p[4], p[5]);
    unsigned a1 = hi ? pk2(p[2], p[3]) : pk2(p[6], p[7]);
    unsigned b0 = (unsigned)__shfl_xor((int)a0, 32, 64);
    unsigned b1 = (unsigned)__shfl_xor((int)a1, 32, 64);
    if (hi) { f0.u[0] = b0; f0.u[1] = b1; f0.u[2] = pk2(p[4], p[5]); f0.u[3] = pk2(p[6], p[7]); }
    else    { f0.u[0] = pk2(p[0], p[1]); f0.u[1] = pk2(p[2], p[3]); f0.u[2] = b0; f0.u[3] = b1; }
    unsigned a2 = hi ? pk2(p[8], p[9])   : pk2(p[12], p[13]);
    unsigned a3 = hi ? pk2(p[10], p[11]) : pk2(p[14], p[15]);
    unsigned b2 = (unsigned)__shfl_xor((int)a2, 32, 64);
    unsigned b3 = (unsigned)__shfl_xor((int)a3, 32, 64);
    if (hi) { f1.u[0] = b2; f1.u[1] = b3; f1.u[2] = pk2(p[12], p[13]); f1.u[3] = pk2(p[14], p[15]); }
    else    { f1.u[0] = pk2(p[8], p[9]); f1.u[1] = pk2(p[10], p[11]); f1.u[2] = b2; f1.u[3] = b3; }
    pfr[0] = f0.v; pfr[1] = f1.v;
  }

  // PV: out[n][dcol] — B-frag: lane holds V[m' = ks*16+hi*8+j][d = dh*32 + (lane&31)]
  f32x16 accO[2];
#pragma unroll
  for (int i = 0; i < 16; ++i) { accO[0][i] = 0.f; accO[1][i] = 0.f; }
  const int dl = lane & 31;
#pragma unroll
  for (int dh = 0; dh < 2; ++dh) {
    int d = dh * 32 + dl;
    int sx = (d ^ (d >> 2)) & 3;
#pragma unroll
    for (int ks = 0; ks < 2; ++ks) {
      bf16x8 vf = *(const bf16x8*)&Vt[wv][d][(((2 * ks + hi) ^ sx) & 3) * 8];
      accO[dh] = __builtin_amdgcn_mfma_f32_32x32x16_bf16(pfr[ks], vf, accO[dh], 0, 0, 0);
    }
  }

  // store: row n = (r&3)+8*(r>>2)+4*hi, cols h*64 + dh*32 + dl
#pragma unroll
  for (int r = 0; r < 16; ++r) {
    int n = (r & 3) + 8 * (r >> 2) + 4 * hi;
    size_t o = (size_t)(w * 32 + n) * 1024 + h * 64 + dl;
    aout[o] = f2bf(accO[0][r]);
    aout[o + 32] = f2bf(accO[1][r]);
  }
}

extern "C" void kernel_launch(void* const* d_in, const int* in_sizes, int n_in,
                              void* d_out, int out_size, void* d_ws, size_t ws_size,
                              hipStream_t stream) {
  const float* x     = (const float*)d_in[0];
  const float* w_qkv = (const float*)d_in[1];
  const float* w_out = (const float*)d_in[2];
  const float* gamma = (const float*)d_in[3];
  const float* beta  = (const float*)d_in[4];

  char* ws = (char*)d_ws;
  unsigned short* wqkv_bf = (unsigned short*)(ws);                       // 6,291,456 B
  unsigned short* wout_bf = (unsigned short*)(ws + 6291456);             // 2,097,152 B
  float* mu    = (float*)(ws + 8388608);                                 // 65,536 B
  float* rstd  = (float*)(ws + 8454144);                                 // 65,536 B
  float* ropeT = (float*)(ws + 8519680);                                 // 8,192 B
  unsigned short* normed = (unsigned short*)(ws + 8527872);              // 33,554,432 B
  unsigned short* qkv    = (unsigned short*)(ws + 42082304);             // 100,663,296 B
  unsigned short* aout   = normed;  // reuse: normed dead after GEMM1

  cvt_kernel<<<3072, 256, 0, stream>>>(w_qkv, wqkv_bf, 3072 * 1024 / 4);
  cvt_kernel<<<1024, 256, 0, stream>>>(w_out, wout_bf, 1024 * 1024 / 4);
  rope_tab_kernel<<<4, 256, 0, stream>>>(ropeT);
  ln_stats_kernel<<<256, 256, 0, stream>>>(x, mu, rstd);
  ln_tr_kernel<<<4096, 256, 0, stream>>>(x, mu, rstd, gamma, beta, normed);
  gemm_kernel<0><<<128 * 24, 256, 0, stream>>>(normed, wqkv_bf, qkv, 3072,
                                               nullptr, nullptr, 16384, 3072, 1024);
  attn_kernel<<<2048, 256, 0, stream>>>(qkv, ropeT, aout);
  gemm_kernel<1><<<128 * 8, 256, 0, stream>>>(aout, wout_bf, nullptr, 0,
                                              x, (float*)d_out, 16384, 1024, 1024);
}

// Round 3
// 232.574 us; speedup vs baseline: 1.5281x; 1.2110x over previous
//
#include <hip/hip_runtime.h>

#define T_TOK 16384
#define C_DIM 1024

typedef float f32x4 __attribute__((ext_vector_type(4)));
typedef float f32x16 __attribute__((ext_vector_type(16)));
typedef __bf16 bf16x8 __attribute__((ext_vector_type(8)));
typedef unsigned short u16x8 __attribute__((ext_vector_type(8)));
typedef unsigned short u16x4 __attribute__((ext_vector_type(4)));

__device__ __forceinline__ unsigned short f2bf(float f) {
  union { float f; unsigned u; } v; v.f = f;
  unsigned r = v.u + 0x7fffu + ((v.u >> 16) & 1u);
  return (unsigned short)(r >> 16);
}
__device__ __forceinline__ float bf2f(unsigned short h) {
  union { unsigned u; float f; } v; v.u = ((unsigned)h) << 16;
  return v.f;
}
__device__ __forceinline__ unsigned pk2(float a, float b) {
  return (unsigned)f2bf(a) | ((unsigned)f2bf(b) << 16);
}

// ---------------- f32 -> bf16 weight conversion ----------------
__global__ __launch_bounds__(256) void cvt_kernel(const float* __restrict__ in,
                                                  unsigned short* __restrict__ out, int n4) {
  int i = blockIdx.x * 256 + threadIdx.x;
  if (i >= n4) return;
  f32x4 v = *(const f32x4*)(in + (size_t)i * 4);
  u16x4 o;
#pragma unroll
  for (int j = 0; j < 4; ++j) o[j] = f2bf(v[j]);
  *(u16x4*)(out + (size_t)i * 4) = o;
}

// ---------------- RoPE table: [32 pos][32 dmod] float2 (cos,sin) ----------------
__global__ __launch_bounds__(256) void rope_tab_kernel(float* __restrict__ tab) {
  int idx = blockIdx.x * 256 + threadIdx.x;
  if (idx >= 1024) return;
  int mm = idx >> 5, d = idx & 31;
  float invf = powf(10000.f, -(float)d * (1.f / 32.f));
  float ang = (float)mm * invf;
  float s, c;
  sincosf(ang, &s, &c);
  tab[idx * 2] = c;
  tab[idx * 2 + 1] = s;
}

// ---------------- LayerNorm stats: mean/rstd per token ----------------
__global__ __launch_bounds__(256) void ln_stats_kernel(const float* __restrict__ x,
                                                       float* __restrict__ mu,
                                                       float* __restrict__ rstd) {
  __shared__ float s1[4][64];
  __shared__ float s2[4][64];
  const int tid = threadIdx.x;
  const int lt = tid & 63, cq = tid >> 6;
  const int t = blockIdx.x * 64 + lt;
  float s = 0.f, ss = 0.f;
  const float* p = x + (size_t)cq * 256 * T_TOK + t;
  for (int c = 0; c < 256; ++c) {
    float v = p[(size_t)c * T_TOK];
    s += v; ss += v * v;
  }
  s1[cq][lt] = s; s2[cq][lt] = ss;
  __syncthreads();
  if (tid < 64) {
    float S  = s1[0][tid] + s1[1][tid] + s1[2][tid] + s1[3][tid];
    float SS = s2[0][tid] + s2[1][tid] + s2[2][tid] + s2[3][tid];
    float m = S * (1.f / 1024.f);
    float var = SS * (1.f / 1024.f) - m * m;
    mu[blockIdx.x * 64 + tid] = m;
    rstd[blockIdx.x * 64 + tid] = rsqrtf(var + 1e-5f);
  }
}

// ---------------- LN apply + transpose: x (C,T) -> normed (T,C) bf16 ----------------
__global__ __launch_bounds__(256) void ln_tr_kernel(const float* __restrict__ x,
                                                    const float* __restrict__ mu,
                                                    const float* __restrict__ rstd,
                                                    const float* __restrict__ gamma,
                                                    const float* __restrict__ beta,
                                                    unsigned short* __restrict__ normed) {
  __shared__ float tile[64][65];
  __shared__ float gs[64], bs[64], ms[64], rs[64];
  const int tid = threadIdx.x;
  const int bt = blockIdx.x & 255;
  const int bc = blockIdx.x >> 8;
  const int t0 = bt * 64, c0 = bc * 64;
  if (tid < 64) {
    gs[tid] = gamma[c0 + tid];
    bs[tid] = beta[c0 + tid];
    ms[tid] = mu[t0 + tid];
    rs[tid] = rstd[t0 + tid];
  }
  const int lc = tid >> 4;
  const int lt4 = (tid & 15) * 4;
#pragma unroll
  for (int r = 0; r < 4; ++r) {
    int c = r * 16 + lc;
    f32x4 v = *(const f32x4*)&x[(size_t)(c0 + c) * T_TOK + t0 + lt4];
    tile[c][lt4 + 0] = v[0]; tile[c][lt4 + 1] = v[1];
    tile[c][lt4 + 2] = v[2]; tile[c][lt4 + 3] = v[3];
  }
  __syncthreads();
#pragma unroll
  for (int r = 0; r < 2; ++r) {
    int idx = r * 256 + tid;
    int t = idx >> 3;
    int c8 = (idx & 7) * 8;
    float m = ms[t], rr = rs[t];
    u16x8 o;
#pragma unroll
    for (int j = 0; j < 8; ++j) {
      float v = tile[c8 + j][t];
      v = (v - m) * rr * gs[c8 + j] + bs[c8 + j];
      o[j] = f2bf(v);
    }
    *(u16x8*)&normed[(size_t)(t0 + t) * C_DIM + c0 + c8] = o;
  }
}

#define GLDS(gp, lp) \
  __builtin_amdgcn_global_load_lds((const __attribute__((address_space(1))) void*)(gp), \
                                   (__attribute__((address_space(3))) void*)(lp), 16, 0, 0)

#define BARX() do { __builtin_amdgcn_sched_barrier(0); __builtin_amdgcn_s_barrier(); \
                    __builtin_amdgcn_sched_barrier(0); } while (0)

// ================= 256x256 8-phase bf16 NT GEMM (T2+T3+T4+T5) =================
// C = A * B^T, A: MxK row-major bf16, B: NxK row-major bf16, out bf16 (ld = ldo).
// 512 threads = 8 waves (2M x 4N); per-wave C: 128x64; BK=64; LDS 128 KiB dbuf.
// LDS swizzle: 16B slot s within a 128B row holds global k-slot s^(row&7);
// staging pre-applies the inverse on the global source (gload_lds dest linear).
__global__ __launch_bounds__(512, 2) void gemm8p_kernel(const unsigned short* __restrict__ A,
                                                        const unsigned short* __restrict__ B,
                                                        unsigned short* __restrict__ Obf,
                                                        int ldo, int nbn, int K) {
  __shared__ unsigned short Lds[2][2][2][8192];  // [op A/B][buf][half][row*64+col]
  const int tid = threadIdx.x;
  const int w = tid >> 6, lane = tid & 63;
  const int wm = w >> 2, wn = w & 3;

  const int nwg = gridDim.x;
  const int orig = blockIdx.x;
  const int wg = (orig & 7) * (nwg >> 3) + (orig >> 3);   // XCD-chunked (grid % 8 == 0)
  const int mt = wg / nbn, nt = wg % nbn;
  const size_t m0 = (size_t)mt * 256, n0 = (size_t)nt * 256;

  // staging source base: row (lane>>3), pre-swizzled k-slot (lane&7)^(lane>>3)
  const unsigned short* gA = A + (m0 + (lane >> 3)) * (size_t)K + ((lane & 7) ^ (lane >> 3)) * 8;
  const unsigned short* gB = B + (n0 + (lane >> 3)) * (size_t)K + ((lane & 7) ^ (lane >> 3)) * 8;
  const int wrow = w * 8;  // this wave's 8-row slice within each 64-row gload

  auto stageA = [&](int b, int h, int kt) {
    const unsigned short* g = gA + (size_t)(h * 128) * K + (size_t)kt * 64;
    GLDS(g + (size_t)wrow * K,        &Lds[0][b][h][wrow * 64]);
    GLDS(g + (size_t)(64 + wrow) * K, &Lds[0][b][h][(64 + wrow) * 64]);
  };
  auto stageB = [&](int b, int h, int kt) {
    const unsigned short* g = gB + (size_t)(h * 128) * K + (size_t)kt * 64;
    GLDS(g + (size_t)wrow * K,        &Lds[1][b][h][wrow * 64]);
    GLDS(g + (size_t)(64 + wrow) * K, &Lds[1][b][h][(64 + wrow) * 64]);
  };

  f32x4 acc[8][4];
#pragma unroll
  for (int i = 0; i < 8; ++i)
#pragma unroll
    for (int j = 0; j < 4; ++j) acc[i][j] = (f32x4){0.f, 0.f, 0.f, 0.f};

  const int KT = K >> 6;  // 64-wide K tiles
  // read-side offsets
  const int off_r = (lane & 15) * 64;                 // row within 16-row frag group
  const int slot0 = (((lane >> 4) ^ (lane & 7)) * 8); // ks=0 swizzled 8-elem slot
  const int slot1 = slot0 ^ 32;                       // ks=1 (slot ^ 4)
  const int boff = (wn & 1) * 4096;                   // 64 rows into B half

  // ---- prologue: tile0 (buf0) fully + A-half0 of tile1 (buf1) ----
  stageA(0, 0, 0); stageA(0, 1, 0); stageB(0, 0, 0); stageB(0, 1, 0);
  if (KT > 1) stageA(1, 0, 1);
  asm volatile("s_waitcnt vmcnt(2)" ::: "memory");
  BARX();

  int bb = 0;
  for (int t = 0; t < KT; ++t, bb ^= 1) {
    const unsigned short* Ab = &Lds[0][bb][wm][0];
    const unsigned short* Bb = &Lds[1][bb][wn >> 1][boff];
    bf16x8 aLo[4][2], aHi[4][2], bLo[2][2], bHi[2][2];

    // ---- P0: read aLo(8) + bLo(4); stage A-half1(t+1) ----
#pragma unroll
    for (int mi = 0; mi < 4; ++mi) {
      aLo[mi][0] = *(const bf16x8*)&Ab[mi * 1024 + off_r + slot0];
      aLo[mi][1] = *(const bf16x8*)&Ab[mi * 1024 + off_r + slot1];
    }
#pragma unroll
    for (int ni = 0; ni < 2; ++ni) {
      bLo[ni][0] = *(const bf16x8*)&Bb[ni * 1024 + off_r + slot0];
      bLo[ni][1] = *(const bf16x8*)&Bb[ni * 1024 + off_r + slot1];
    }
    if (t + 1 < KT) stageA(bb ^ 1, 1, t + 1);
    BARX();
    __builtin_amdgcn_s_setprio(1);
#pragma unroll
    for (int mi = 0; mi < 4; ++mi)
#pragma unroll
      for (int ni = 0; ni < 2; ++ni)
#pragma unroll
        for (int ks = 0; ks < 2; ++ks)
          acc[mi][ni] = __builtin_amdgcn_mfma_f32_16x16x32_bf16(aLo[mi][ks], bLo[ni][ks], acc[mi][ni], 0, 0, 0);
    __builtin_amdgcn_s_setprio(0);
    BARX();

    // ---- P1: read bHi(4); stage B-half0(t+1) ----
#pragma unroll
    for (int ni = 0; ni < 2; ++ni) {
      bHi[ni][0] = *(const bf16x8*)&Bb[(ni + 2) * 1024 + off_r + slot0];
      bHi[ni][1] = *(const bf16x8*)&Bb[(ni + 2) * 1024 + off_r + slot1];
    }
    if (t + 1 < KT) stageB(bb ^ 1, 0, t + 1);
    BARX();
    __builtin_amdgcn_s_setprio(1);
#pragma unroll
    for (int mi = 0; mi < 4; ++mi)
#pragma unroll
      for (int ni = 0; ni < 2; ++ni)
#pragma unroll
        for (int ks = 0; ks < 2; ++ks)
          acc[mi][ni + 2] = __builtin_amdgcn_mfma_f32_16x16x32_bf16(aLo[mi][ks], bHi[ni][ks], acc[mi][ni + 2], 0, 0, 0);
    __builtin_amdgcn_s_setprio(0);
    BARX();

    // ---- P2: read aHi(8); stage B-half1(t+1) ----
#pragma unroll
    for (int mi = 0; mi < 4; ++mi) {
      aHi[mi][0] = *(const bf16x8*)&Ab[(mi + 4) * 1024 + off_r + slot0];
      aHi[mi][1] = *(const bf16x8*)&Ab[(mi + 4) * 1024 + off_r + slot1];
    }
    if (t + 1 < KT) stageB(bb ^ 1, 1, t + 1);
    BARX();
    __builtin_amdgcn_s_setprio(1);
#pragma unroll
    for (int mi = 0; mi < 4; ++mi)
#pragma unroll
      for (int ni = 0; ni < 2; ++ni)
#pragma unroll
        for (int ks = 0; ks < 2; ++ks)
          acc[mi + 4][ni + 2] = __builtin_amdgcn_mfma_f32_16x16x32_bf16(aHi[mi][ks], bHi[ni][ks], acc[mi + 4][ni + 2], 0, 0, 0);
    __builtin_amdgcn_s_setprio(0);
    BARX();

    // ---- P3: no reads; stage A-half0(t+2) into CURRENT buf (A dead after P2);
    //         counted vmcnt guarantees tile t+1 fully landed ----
    if (t + 2 < KT) {
      stageA(bb, 0, t + 2);
      asm volatile("s_waitcnt vmcnt(2)" ::: "memory");
    } else {
      asm volatile("s_waitcnt vmcnt(0)" ::: "memory");
    }
    BARX();
    __builtin_amdgcn_s_setprio(1);
#pragma unroll
    for (int mi = 0; mi < 4; ++mi)
#pragma unroll
      for (int ni = 0; ni < 2; ++ni)
#pragma unroll
        for (int ks = 0; ks < 2; ++ks)
          acc[mi + 4][ni] = __builtin_amdgcn_mfma_f32_16x16x32_bf16(aHi[mi][ks], bLo[ni][ks], acc[mi + 4][ni], 0, 0, 0);
    __builtin_amdgcn_s_setprio(0);
    BARX();
  }

  // ---- epilogue: repack via LDS for coalesced u16x8 stores ----
  unsigned short* cw = &Lds[0][0][0][0] + (size_t)w * 8192;  // wave-private [128][64]
#pragma unroll
  for (int mi = 0; mi < 8; ++mi)
#pragma unroll
    for (int ni = 0; ni < 4; ++ni)
#pragma unroll
      for (int r = 0; r < 4; ++r)
        cw[(mi * 16 + (lane >> 4) * 4 + r) * 64 + ni * 16 + (lane & 15)] = f2bf(acc[mi][ni][r]);
  __syncthreads();
  const size_t gr0 = m0 + wm * 128;
  const size_t gc0 = n0 + wn * 64;
#pragma unroll
  for (int it = 0; it < 16; ++it) {
    int idx = it * 64 + lane;
    int rr = idx >> 3, c8 = (idx & 7) * 8;
    *(u16x8*)&Obf[(gr0 + rr) * (size_t)ldo + gc0 + c8] = *(const u16x8*)&cw[rr * 64 + c8];
  }
}

// ---------------- bf16 NT GEMM, 128x128 tile (m97 structure) — GEMM2 only ----------------
template <int EPI>
__global__ __launch_bounds__(256) void gemm_kernel(const unsigned short* __restrict__ A,
                                                   const unsigned short* __restrict__ B,
                                                   unsigned short* __restrict__ Obf, int ldo,
                                                   const float* __restrict__ Xadd,
                                                   float* __restrict__ Ofp,
                                                   int M, int N, int K) {
  __shared__ unsigned short Al[2][128 * 32];
  __shared__ unsigned short Bl[2][128 * 32];
  const int tid = threadIdx.x;
  const int wid = tid >> 6, lane = tid & 63;
  const int nbn = N >> 7;
  const int nwg = gridDim.x;
  const int orig = blockIdx.x;
  const int wg = (orig & 7) * (nwg >> 3) + (orig >> 3);
  const int mt = wg / nbn;   // row-major: consecutive wg share A-band, stream small B
  const int nt = wg % nbn;
  const size_t m0 = (size_t)mt * 128, n0 = (size_t)nt * 128;
  const int wr = wid >> 1, wc = wid & 1;

  const int srow = lane >> 2;
  const int skh = (lane & 3) * 8;
  const int ch0 = wid * 2, ch1 = wid * 2 + 1;
  const unsigned short* a0 = A + (m0 + ch0 * 16 + srow) * (size_t)K + skh;
  const unsigned short* a1 = A + (m0 + ch1 * 16 + srow) * (size_t)K + skh;
  const unsigned short* b0 = B + (n0 + ch0 * 16 + srow) * (size_t)K + skh;
  const unsigned short* b1 = B + (n0 + ch1 * 16 + srow) * (size_t)K + skh;

  auto stage = [&](int buf, int k0) {
    GLDS(a0 + k0, &Al[buf][ch0 * 512]);
    GLDS(a1 + k0, &Al[buf][ch1 * 512]);
    GLDS(b0 + k0, &Bl[buf][ch0 * 512]);
    GLDS(b1 + k0, &Bl[buf][ch1 * 512]);
  };

  f32x4 acc[4][4];
#pragma unroll
  for (int i = 0; i < 4; ++i)
#pragma unroll
    for (int j = 0; j < 4; ++j) acc[i][j] = (f32x4){0.f, 0.f, 0.f, 0.f};

  const int KS = K >> 5;
  const int arow = wr * 64 + (lane & 15);
  const int brow = wc * 64 + (lane & 15);
  const int koff = (lane >> 4) * 8;

  stage(0, 0);
  int buf = 0;
  for (int ks = 0; ks < KS; ++ks) {
    __syncthreads();
    if (ks + 1 < KS) stage(buf ^ 1, (ks + 1) * 32);
    bf16x8 af[4], bfr[4];
#pragma unroll
    for (int mi = 0; mi < 4; ++mi)
      af[mi] = *(const bf16x8*)&Al[buf][(arow + mi * 16) * 32 + koff];
#pragma unroll
    for (int ni = 0; ni < 4; ++ni)
      bfr[ni] = *(const bf16x8*)&Bl[buf][(brow + ni * 16) * 32 + koff];
#pragma unroll
    for (int mi = 0; mi < 4; ++mi)
#pragma unroll
      for (int ni = 0; ni < 4; ++ni)
        acc[mi][ni] = __builtin_amdgcn_mfma_f32_16x16x32_bf16(af[mi], bfr[ni], acc[mi][ni], 0, 0, 0);
    buf ^= 1;
  }

  const int r0 = wr * 64 + (lane >> 4) * 4;
  const int ccol = wc * 64 + (lane & 15);
  if (EPI == 0) {
#pragma unroll
    for (int mi = 0; mi < 4; ++mi) {
      size_t trow = m0 + r0 + mi * 16;
#pragma unroll
      for (int ni = 0; ni < 4; ++ni) {
        size_t col = n0 + ccol + ni * 16;
#pragma unroll
        for (int r = 0; r < 4; ++r)
          Obf[(trow + r) * (size_t)ldo + col] = f2bf(acc[mi][ni][r]);
      }
    }
  } else {
#pragma unroll
    for (int mi = 0; mi < 4; ++mi) {
      size_t trow = m0 + r0 + mi * 16;
#pragma unroll
      for (int ni = 0; ni < 4; ++ni) {
        size_t col = n0 + ccol + ni * 16;
        f32x4 xv = *(const f32x4*)&Xadd[col * T_TOK + trow];
        f32x4 o = acc[mi][ni] + xv;
        *(f32x4*)&Ofp[col * T_TOK + trow] = o;
      }
    }
  }
}

// ---------------- MFMA windowed attention with RoPE ----------------
__global__ __launch_bounds__(256) void attn_kernel(const unsigned short* __restrict__ qkv,
                                                   const float* __restrict__ ropeT,
                                                   unsigned short* __restrict__ aout) {
  __shared__ unsigned short Vt[4][64][32];
  const int tid = threadIdx.x;
  const int wv = tid >> 6;
  const int lane = tid & 63;
  const int m = lane & 31;
  const int hi = lane >> 5;
  const int gw = blockIdx.x * 4 + wv;
  const int w = gw >> 4, h = gw & 15;
  const size_t rowbase = ((size_t)(w * 32 + m)) * 3072 + (size_t)h * 64;
  const unsigned short* qp = qkv + rowbase;

  u16x8 qv[4], kv[4], vv[4];
#pragma unroll
  for (int s = 0; s < 4; ++s) {
    int off = s * 16 + hi * 8;
    qv[s] = *(const u16x8*)(qp + off);
    kv[s] = *(const u16x8*)(qp + 1024 + off);
    vv[s] = *(const u16x8*)(qp + 2048 + off);
  }

#pragma unroll
  for (int s = 0; s < 4; ++s)
#pragma unroll
    for (int j = 0; j < 8; ++j) {
      int d = s * 16 + hi * 8 + j;
      int slot = (((m >> 3) ^ (d ^ (d >> 2))) & 3) * 8 + (m & 7);
      Vt[wv][d][slot] = vv[s][j];
    }

  f32x4 ct[2][4];
  const float* tp = ropeT + (size_t)(m * 32 + hi * 8) * 2;
#pragma unroll
  for (int kp = 0; kp < 2; ++kp)
#pragma unroll
    for (int q = 0; q < 4; ++q)
      ct[kp][q] = *(const f32x4*)(tp + kp * 32 + q * 4);

  union FU { unsigned u[4]; bf16x8 v; };
  bf16x8 qfr[4], kfr[4];
#pragma unroll
  for (int ks = 0; ks < 4; ++ks) {
    const int kp = ks & 1;
    FU fq, fk;
#pragma unroll
    for (int jp = 0; jp < 4; ++jp) {
      float c0 = ct[kp][jp][0], s0 = ct[kp][jp][1];
      float c1 = ct[kp][jp][2], s1 = ct[kp][jp][3];
      float q0 = bf2f(qv[ks][2 * jp]), q1 = bf2f(qv[ks][2 * jp + 1]);
      float k0 = bf2f(kv[ks][2 * jp]), k1 = bf2f(kv[ks][2 * jp + 1]);
      float rq0, rq1, rk0, rk1;
      if (ks < 2) {
        rq0 = -bf2f(qv[ks + 2][2 * jp]); rq1 = -bf2f(qv[ks + 2][2 * jp + 1]);
        rk0 = -bf2f(kv[ks + 2][2 * jp]); rk1 = -bf2f(kv[ks + 2][2 * jp + 1]);
      } else {
        rq0 = bf2f(qv[ks - 2][2 * jp]); rq1 = bf2f(qv[ks - 2][2 * jp + 1]);
        rk0 = bf2f(kv[ks - 2][2 * jp]); rk1 = bf2f(kv[ks - 2][2 * jp + 1]);
      }
      fq.u[jp] = pk2(q0 * c0 + rq0 * s0, q1 * c1 + rq1 * s1);
      fk.u[jp] = pk2(k0 * c0 + rk0 * s0, k1 * c1 + rk1 * s1);
    }
    qfr[ks] = fq.v; kfr[ks] = fk.v;
  }

  f32x16 accS;
#pragma unroll
  for (int i = 0; i < 16; ++i) accS[i] = 0.f;
#pragma unroll
  for (int ks = 0; ks < 4; ++ks)
    accS = __builtin_amdgcn_mfma_f32_32x32x16_bf16(kfr[ks], qfr[ks], accS, 0, 0, 0);

  float p[16];
  float mx = -1e30f;
#pragma unroll
  for (int r = 0; r < 16; ++r) { p[r] = accS[r] * 0.125f; mx = fmaxf(mx, p[r]); }
  mx = fmaxf(mx, __shfl_xor(mx, 32, 64));
  float sum = 0.f;
#pragma unroll
  for (int r = 0; r < 16; ++r) { p[r] = __expf(p[r] - mx); sum += p[r]; }
  sum += __shfl_xor(sum, 32, 64);
  const float inv = 1.f / sum;
#pragma unroll
  for (int r = 0; r < 16; ++r) p[r] *= inv;

  bf16x8 pfr[2];
  {
    FU f0, f1;
    unsigned a0 = hi ? pk2(p[0], p[1]) : pk2(p[4], p[5]);
    unsigned a1 = hi ? pk2(p[2], p[3]) : pk2(p[6], p[7]);
    unsigned b0 = (unsigned)__shfl_xor((int)a0, 32, 64);
    unsigned b1 = (unsigned)__shfl_xor((int)a1, 32, 64);
    if (hi) { f0.u[0] = b0; f0.u[1] = b1; f0.u[2] = pk2(p[4], p[5]); f0.u[3] = pk2(p[6], p[7]); }
    else    { f0.u[0] = pk2(p[0], p[1]); f0.u[1] = pk2(p[2], p[3]); f0.u[2] = b0; f0.u[3] = b1; }
    unsigned a2 = hi ? pk2(p[8], p[9])   : pk2(p[12], p[13]);
    unsigned a3 = hi ? pk2(p[10], p[11]) : pk2(p[14], p[15]);
    unsigned b2 = (unsigned)__shfl_xor((int)a2, 32, 64);
    unsigned b3 = (unsigned)__shfl_xor((int)a3, 32, 64);
    if (hi) { f1.u[0] = b2; f1.u[1] = b3; f1.u[2] = pk2(p[12], p[13]); f1.u[3] = pk2(p[14], p[15]); }
    else    { f1.u[0] = pk2(p[8], p[9]); f1.u[1] = pk2(p[10], p[11]); f1.u[2] = b2; f1.u[3] = b3; }
    pfr[0] = f0.v; pfr[1] = f1.v;
  }

  f32x16 accO[2];
#pragma unroll
  for (int i = 0; i < 16; ++i) { accO[0][i] = 0.f; accO[1][i] = 0.f; }
  const int dl = lane & 31;
#pragma unroll
  for (int dh = 0; dh < 2; ++dh) {
    int d = dh * 32 + dl;
    int sx = (d ^ (d >> 2)) & 3;
#pragma unroll
    for (int ks = 0; ks < 2; ++ks) {
      bf16x8 vf = *(const bf16x8*)&Vt[wv][d][(((2 * ks + hi) ^ sx) & 3) * 8];
      accO[dh] = __builtin_amdgcn_mfma_f32_32x32x16_bf16(pfr[ks], vf, accO[dh], 0, 0, 0);
    }
  }

#pragma unroll
  for (int r = 0; r < 16; ++r) {
    int n = (r & 3) + 8 * (r >> 2) + 4 * hi;
    size_t o = (size_t)(w * 32 + n) * 1024 + h * 64 + dl;
    aout[o] = f2bf(accO[0][r]);
    aout[o + 32] = f2bf(accO[1][r]);
  }
}

extern "C" void kernel_launch(void* const* d_in, const int* in_sizes, int n_in,
                              void* d_out, int out_size, void* d_ws, size_t ws_size,
                              hipStream_t stream) {
  const float* x     = (const float*)d_in[0];
  const float* w_qkv = (const float*)d_in[1];
  const float* w_out = (const float*)d_in[2];
  const float* gamma = (const float*)d_in[3];
  const float* beta  = (const float*)d_in[4];

  char* ws = (char*)d_ws;
  unsigned short* wqkv_bf = (unsigned short*)(ws);                       // 6,291,456 B
  unsigned short* wout_bf = (unsigned short*)(ws + 6291456);             // 2,097,152 B
  float* mu    = (float*)(ws + 8388608);                                 // 65,536 B
  float* rstd  = (float*)(ws + 8454144);                                 // 65,536 B
  float* ropeT = (float*)(ws + 8519680);                                 // 8,192 B
  unsigned short* normed = (unsigned short*)(ws + 8527872);              // 33,554,432 B
  unsigned short* qkv    = (unsigned short*)(ws + 42082304);             // 100,663,296 B
  unsigned short* aout   = normed;  // reuse: normed dead after GEMM1

  cvt_kernel<<<3072, 256, 0, stream>>>(w_qkv, wqkv_bf, 3072 * 1024 / 4);
  cvt_kernel<<<1024, 256, 0, stream>>>(w_out, wout_bf, 1024 * 1024 / 4);
  rope_tab_kernel<<<4, 256, 0, stream>>>(ropeT);
  ln_stats_kernel<<<256, 256, 0, stream>>>(x, mu, rstd);
  ln_tr_kernel<<<4096, 256, 0, stream>>>(x, mu, rstd, gamma, beta, normed);
  // GEMM1: 16384x3072x1024, 256^2 tiles -> grid 64*12 = 768
  gemm8p_kernel<<<768, 512, 0, stream>>>(normed, wqkv_bf, qkv, 3072, 12, 1024);
  attn_kernel<<<2048, 256, 0, stream>>>(qkv, ropeT, aout);
  gemm_kernel<1><<<128 * 8, 256, 0, stream>>>(aout, wout_bf, nullptr, 0,
                                              x, (float*)d_out, 16384, 1024, 1024);
}

// Round 4
// 220.358 us; speedup vs baseline: 1.6128x; 1.0554x over previous
//
#include <hip/hip_runtime.h>

#define T_TOK 16384
#define C_DIM 1024

typedef float f32x4 __attribute__((ext_vector_type(4)));
typedef float f32x16 __attribute__((ext_vector_type(16)));
typedef __bf16 bf16x8 __attribute__((ext_vector_type(8)));
typedef unsigned short u16x8 __attribute__((ext_vector_type(8)));
typedef unsigned short u16x4 __attribute__((ext_vector_type(4)));

__device__ __forceinline__ unsigned short f2bf(float f) {
  union { float f; unsigned u; } v; v.f = f;
  unsigned r = v.u + 0x7fffu + ((v.u >> 16) & 1u);
  return (unsigned short)(r >> 16);
}
__device__ __forceinline__ float bf2f(unsigned short h) {
  union { unsigned u; float f; } v; v.u = ((unsigned)h) << 16;
  return v.f;
}
__device__ __forceinline__ unsigned pk2(float a, float b) {
  return (unsigned)f2bf(a) | ((unsigned)f2bf(b) << 16);
}

// ---------------- f32 -> bf16 weight conversion ----------------
__global__ __launch_bounds__(256) void cvt_kernel(const float* __restrict__ in,
                                                  unsigned short* __restrict__ out, int n4) {
  int i = blockIdx.x * 256 + threadIdx.x;
  if (i >= n4) return;
  f32x4 v = *(const f32x4*)(in + (size_t)i * 4);
  u16x4 o;
#pragma unroll
  for (int j = 0; j < 4; ++j) o[j] = f2bf(v[j]);
  *(u16x4*)(out + (size_t)i * 4) = o;
}

// ---------------- RoPE table: [32 pos][32 dmod] float2 (cos,sin) ----------------
__global__ __launch_bounds__(256) void rope_tab_kernel(float* __restrict__ tab) {
  int idx = blockIdx.x * 256 + threadIdx.x;
  if (idx >= 1024) return;
  int mm = idx >> 5, d = idx & 31;
  float invf = powf(10000.f, -(float)d * (1.f / 32.f));
  float ang = (float)mm * invf;
  float s, c;
  sincosf(ang, &s, &c);
  tab[idx * 2] = c;
  tab[idx * 2 + 1] = s;
}

// ---------------- LayerNorm stats: mean/rstd per token ----------------
__global__ __launch_bounds__(256) void ln_stats_kernel(const float* __restrict__ x,
                                                       float* __restrict__ mu,
                                                       float* __restrict__ rstd) {
  __shared__ float s1[4][64];
  __shared__ float s2[4][64];
  const int tid = threadIdx.x;
  const int lt = tid & 63, cq = tid >> 6;
  const int t = blockIdx.x * 64 + lt;
  float s = 0.f, ss = 0.f;
  const float* p = x + (size_t)cq * 256 * T_TOK + t;
  for (int c = 0; c < 256; ++c) {
    float v = p[(size_t)c * T_TOK];
    s += v; ss += v * v;
  }
  s1[cq][lt] = s; s2[cq][lt] = ss;
  __syncthreads();
  if (tid < 64) {
    float S  = s1[0][tid] + s1[1][tid] + s1[2][tid] + s1[3][tid];
    float SS = s2[0][tid] + s2[1][tid] + s2[2][tid] + s2[3][tid];
    float m = S * (1.f / 1024.f);
    float var = SS * (1.f / 1024.f) - m * m;
    mu[blockIdx.x * 64 + tid] = m;
    rstd[blockIdx.x * 64 + tid] = rsqrtf(var + 1e-5f);
  }
}

// ---------------- LN apply + transpose: x (C,T) -> normed (T,C) bf16 ----------------
__global__ __launch_bounds__(256) void ln_tr_kernel(const float* __restrict__ x,
                                                    const float* __restrict__ mu,
                                                    const float* __restrict__ rstd,
                                                    const float* __restrict__ gamma,
                                                    const float* __restrict__ beta,
                                                    unsigned short* __restrict__ normed) {
  __shared__ float tile[64][65];
  __shared__ float gs[64], bs[64], ms[64], rs[64];
  const int tid = threadIdx.x;
  const int bt = blockIdx.x & 255;
  const int bc = blockIdx.x >> 8;
  const int t0 = bt * 64, c0 = bc * 64;
  if (tid < 64) {
    gs[tid] = gamma[c0 + tid];
    bs[tid] = beta[c0 + tid];
    ms[tid] = mu[t0 + tid];
    rs[tid] = rstd[t0 + tid];
  }
  const int lc = tid >> 4;
  const int lt4 = (tid & 15) * 4;
#pragma unroll
  for (int r = 0; r < 4; ++r) {
    int c = r * 16 + lc;
    f32x4 v = *(const f32x4*)&x[(size_t)(c0 + c) * T_TOK + t0 + lt4];
    tile[c][lt4 + 0] = v[0]; tile[c][lt4 + 1] = v[1];
    tile[c][lt4 + 2] = v[2]; tile[c][lt4 + 3] = v[3];
  }
  __syncthreads();
#pragma unroll
  for (int r = 0; r < 2; ++r) {
    int idx = r * 256 + tid;
    int t = idx >> 3;
    int c8 = (idx & 7) * 8;
    float m = ms[t], rr = rs[t];
    u16x8 o;
#pragma unroll
    for (int j = 0; j < 8; ++j) {
      float v = tile[c8 + j][t];
      v = (v - m) * rr * gs[c8 + j] + bs[c8 + j];
      o[j] = f2bf(v);
    }
    *(u16x8*)&normed[(size_t)(t0 + t) * C_DIM + c0 + c8] = o;
  }
}

#define GLDS(gp, lp) \
  __builtin_amdgcn_global_load_lds((const __attribute__((address_space(1))) void*)(gp), \
                                   (__attribute__((address_space(3))) void*)(lp), 16, 0, 0)

#define BAR() __builtin_amdgcn_s_barrier()
#define LGKM0() asm volatile("s_waitcnt lgkmcnt(0)" ::: "memory")

// ================= 256x256 8-phase bf16 NT GEMM (T2+T3+T4+T5) =================
// C = A * B^T, A: MxK row-major bf16, B: NxK row-major bf16.
// EPI 0: bf16 out (ld=ldo) via wave-private LDS repack.
// EPI 1: f32 transposed out + residual: Ofp[col*T_TOK+row] = acc + Xadd[col*T_TOK+row].
// 512 threads = 8 waves (2M x 4N); per-wave C: 128x64; BK=64; LDS 128 KiB dbuf.
// Block map: each XCD owns an 8-row mt band, mt-fast order (L2 panel reuse).
template <int EPI>
__global__ __launch_bounds__(512, 2) void gemm8p_kernel(const unsigned short* __restrict__ A,
                                                        const unsigned short* __restrict__ B,
                                                        unsigned short* __restrict__ Obf,
                                                        int ldo, int nbn, int K,
                                                        const float* __restrict__ Xadd,
                                                        float* __restrict__ Ofp) {
  __shared__ unsigned short Lds[2][2][2][8192];  // [op A/B][buf][half][row*64+col]
  const int tid = threadIdx.x;
  const int w = tid >> 6, lane = tid & 63;
  const int wm = w >> 2, wn = w & 3;

  // XCD-banded, mt-fast block mapping (requires nbm % 8 == 0)
  const int nbm = gridDim.x / nbn;
  const int mtpx = nbm >> 3;
  const int xcd = blockIdx.x & 7;
  const int ib = blockIdx.x >> 3;
  const int mt = xcd * mtpx + (ib % mtpx);
  const int nt = ib / mtpx;
  const size_t m0 = (size_t)mt * 256, n0 = (size_t)nt * 256;

  // staging source base: row (lane>>3), pre-swizzled k-slot (lane&7)^(lane>>3)
  const unsigned short* gA = A + (m0 + (lane >> 3)) * (size_t)K + ((lane & 7) ^ (lane >> 3)) * 8;
  const unsigned short* gB = B + (n0 + (lane >> 3)) * (size_t)K + ((lane & 7) ^ (lane >> 3)) * 8;
  const int wrow = w * 8;  // this wave's 8-row slice within each 64-row gload

  auto stageA = [&](int b, int h, int kt) {
    const unsigned short* g = gA + (size_t)(h * 128) * K + (size_t)kt * 64;
    GLDS(g + (size_t)wrow * K,        &Lds[0][b][h][wrow * 64]);
    GLDS(g + (size_t)(64 + wrow) * K, &Lds[0][b][h][(64 + wrow) * 64]);
  };
  auto stageB = [&](int b, int h, int kt) {
    const unsigned short* g = gB + (size_t)(h * 128) * K + (size_t)kt * 64;
    GLDS(g + (size_t)wrow * K,        &Lds[1][b][h][wrow * 64]);
    GLDS(g + (size_t)(64 + wrow) * K, &Lds[1][b][h][(64 + wrow) * 64]);
  };

  f32x4 acc[8][4];
#pragma unroll
  for (int i = 0; i < 8; ++i)
#pragma unroll
    for (int j = 0; j < 4; ++j) acc[i][j] = (f32x4){0.f, 0.f, 0.f, 0.f};

  const int KT = K >> 6;
  const int off_r = (lane & 15) * 64;
  const int slot0 = (((lane >> 4) ^ (lane & 7)) * 8);
  const int slot1 = slot0 ^ 32;
  const int boff = (wn & 1) * 4096;

  // ---- prologue: tile0 (buf0) fully + A-half0 of tile1 (buf1) ----
  stageA(0, 0, 0); stageA(0, 1, 0); stageB(0, 0, 0); stageB(0, 1, 0);
  if (KT > 1) stageA(1, 0, 1);
  asm volatile("s_waitcnt vmcnt(2)" ::: "memory");
  BAR();

  int bb = 0;
  for (int t = 0; t < KT; ++t, bb ^= 1) {
    const unsigned short* Ab = &Lds[0][bb][wm][0];
    const unsigned short* Bb = &Lds[1][bb][wn >> 1][boff];
    bf16x8 aLo[4][2], aHi[4][2], bLo[2][2], bHi[2][2];

    // ---- P0: read aLo(8) + bLo(4); stage A-half1(t+1) ----
#pragma unroll
    for (int mi = 0; mi < 4; ++mi) {
      aLo[mi][0] = *(const bf16x8*)&Ab[mi * 1024 + off_r + slot0];
      aLo[mi][1] = *(const bf16x8*)&Ab[mi * 1024 + off_r + slot1];
    }
#pragma unroll
    for (int ni = 0; ni < 2; ++ni) {
      bLo[ni][0] = *(const bf16x8*)&Bb[ni * 1024 + off_r + slot0];
      bLo[ni][1] = *(const bf16x8*)&Bb[ni * 1024 + off_r + slot1];
    }
    if (t + 1 < KT) stageA(bb ^ 1, 1, t + 1);
    BAR();
    LGKM0();
    __builtin_amdgcn_s_setprio(1);
#pragma unroll
    for (int mi = 0; mi < 4; ++mi)
#pragma unroll
      for (int ni = 0; ni < 2; ++ni)
#pragma unroll
        for (int ks = 0; ks < 2; ++ks)
          acc[mi][ni] = __builtin_amdgcn_mfma_f32_16x16x32_bf16(aLo[mi][ks], bLo[ni][ks], acc[mi][ni], 0, 0, 0);
    __builtin_amdgcn_s_setprio(0);
    BAR();

    // ---- P1: read bHi(4); stage B-half0(t+1) ----
#pragma unroll
    for (int ni = 0; ni < 2; ++ni) {
      bHi[ni][0] = *(const bf16x8*)&Bb[(ni + 2) * 1024 + off_r + slot0];
      bHi[ni][1] = *(const bf16x8*)&Bb[(ni + 2) * 1024 + off_r + slot1];
    }
    if (t + 1 < KT) stageB(bb ^ 1, 0, t + 1);
    BAR();
    LGKM0();
    __builtin_amdgcn_s_setprio(1);
#pragma unroll
    for (int mi = 0; mi < 4; ++mi)
#pragma unroll
      for (int ni = 0; ni < 2; ++ni)
#pragma unroll
        for (int ks = 0; ks < 2; ++ks)
          acc[mi][ni + 2] = __builtin_amdgcn_mfma_f32_16x16x32_bf16(aLo[mi][ks], bHi[ni][ks], acc[mi][ni + 2], 0, 0, 0);
    __builtin_amdgcn_s_setprio(0);
    BAR();

    // ---- P2: read aHi(8); stage B-half1(t+1) ----
#pragma unroll
    for (int mi = 0; mi < 4; ++mi) {
      aHi[mi][0] = *(const bf16x8*)&Ab[(mi + 4) * 1024 + off_r + slot0];
      aHi[mi][1] = *(const bf16x8*)&Ab[(mi + 4) * 1024 + off_r + slot1];
    }
    if (t + 1 < KT) stageB(bb ^ 1, 1, t + 1);
    BAR();
    LGKM0();
    __builtin_amdgcn_s_setprio(1);
#pragma unroll
    for (int mi = 0; mi < 4; ++mi)
#pragma unroll
      for (int ni = 0; ni < 2; ++ni)
#pragma unroll
        for (int ks = 0; ks < 2; ++ks)
          acc[mi + 4][ni + 2] = __builtin_amdgcn_mfma_f32_16x16x32_bf16(aHi[mi][ks], bHi[ni][ks], acc[mi + 4][ni + 2], 0, 0, 0);
    __builtin_amdgcn_s_setprio(0);
    BAR();

    // ---- P3: stage A-half0(t+2) into CURRENT buf (A-half0 dead after P1 reads);
    //         counted vmcnt guarantees tile t+1 fully landed ----
    if (t + 2 < KT) {
      stageA(bb, 0, t + 2);
      asm volatile("s_waitcnt vmcnt(2)" ::: "memory");
    } else {
      asm volatile("s_waitcnt vmcnt(0)" ::: "memory");
    }
    BAR();
    __builtin_amdgcn_s_setprio(1);
#pragma unroll
    for (int mi = 0; mi < 4; ++mi)
#pragma unroll
      for (int ni = 0; ni < 2; ++ni)
#pragma unroll
        for (int ks = 0; ks < 2; ++ks)
          acc[mi + 4][ni] = __builtin_amdgcn_mfma_f32_16x16x32_bf16(aHi[mi][ks], bLo[ni][ks], acc[mi + 4][ni], 0, 0, 0);
    __builtin_amdgcn_s_setprio(0);
    BAR();
  }

  if (EPI == 0) {
    // wave-private LDS repack -> coalesced u16x8 stores (no cross-wave sync needed)
    unsigned short* cw = &Lds[0][0][0][0] + (size_t)w * 8192;
#pragma unroll
    for (int mi = 0; mi < 8; ++mi)
#pragma unroll
      for (int ni = 0; ni < 4; ++ni)
#pragma unroll
        for (int r = 0; r < 4; ++r)
          cw[(mi * 16 + (lane >> 4) * 4 + r) * 64 + ni * 16 + (lane & 15)] = f2bf(acc[mi][ni][r]);
    LGKM0();
    const size_t gr0 = m0 + wm * 128;
    const size_t gc0 = n0 + wn * 64;
#pragma unroll
    for (int it = 0; it < 16; ++it) {
      int idx = it * 64 + lane;
      int rr = idx >> 3, c8 = (idx & 7) * 8;
      *(u16x8*)&Obf[(gr0 + rr) * (size_t)ldo + gc0 + c8] = *(const u16x8*)&cw[rr * 64 + c8];
    }
  } else {
    // f32 transposed + residual; lanes {l,l+16,l+32,l+48} cover 64 consecutive bytes
    const size_t gr0 = m0 + wm * 128 + (lane >> 4) * 4;
    const size_t gc0 = n0 + wn * 64 + (lane & 15);
#pragma unroll
    for (int mi = 0; mi < 8; ++mi) {
      size_t row = gr0 + mi * 16;
#pragma unroll
      for (int ni = 0; ni < 4; ++ni) {
        size_t col = gc0 + ni * 16;
        f32x4 xv = *(const f32x4*)&Xadd[col * T_TOK + row];
        f32x4 o = acc[mi][ni] + xv;
        *(f32x4*)&Ofp[col * T_TOK + row] = o;
      }
    }
  }
}

// ---------------- MFMA windowed attention with RoPE ----------------
__global__ __launch_bounds__(256) void attn_kernel(const unsigned short* __restrict__ qkv,
                                                   const float* __restrict__ ropeT,
                                                   unsigned short* __restrict__ aout) {
  __shared__ unsigned short Vt[4][64][32];
  const int tid = threadIdx.x;
  const int wv = tid >> 6;
  const int lane = tid & 63;
  const int m = lane & 31;
  const int hi = lane >> 5;
  const int gw = blockIdx.x * 4 + wv;
  const int w = gw >> 4, h = gw & 15;
  const size_t rowbase = ((size_t)(w * 32 + m)) * 3072 + (size_t)h * 64;
  const unsigned short* qp = qkv + rowbase;

  u16x8 qv[4], kv[4], vv[4];
#pragma unroll
  for (int s = 0; s < 4; ++s) {
    int off = s * 16 + hi * 8;
    qv[s] = *(const u16x8*)(qp + off);
    kv[s] = *(const u16x8*)(qp + 1024 + off);
    vv[s] = *(const u16x8*)(qp + 2048 + off);
  }

#pragma unroll
  for (int s = 0; s < 4; ++s)
#pragma unroll
    for (int j = 0; j < 8; ++j) {
      int d = s * 16 + hi * 8 + j;
      int slot = (((m >> 3) ^ (d ^ (d >> 2))) & 3) * 8 + (m & 7);
      Vt[wv][d][slot] = vv[s][j];
    }

  f32x4 ct[2][4];
  const float* tp = ropeT + (size_t)(m * 32 + hi * 8) * 2;
#pragma unroll
  for (int kp = 0; kp < 2; ++kp)
#pragma unroll
    for (int q = 0; q < 4; ++q)
      ct[kp][q] = *(const f32x4*)(tp + kp * 32 + q * 4);

  union FU { unsigned u[4]; bf16x8 v; };
  bf16x8 qfr[4], kfr[4];
#pragma unroll
  for (int ks = 0; ks < 4; ++ks) {
    const int kp = ks & 1;
    FU fq, fk;
#pragma unroll
    for (int jp = 0; jp < 4; ++jp) {
      float c0 = ct[kp][jp][0], s0 = ct[kp][jp][1];
      float c1 = ct[kp][jp][2], s1 = ct[kp][jp][3];
      float q0 = bf2f(qv[ks][2 * jp]), q1 = bf2f(qv[ks][2 * jp + 1]);
      float k0 = bf2f(kv[ks][2 * jp]), k1 = bf2f(kv[ks][2 * jp + 1]);
      float rq0, rq1, rk0, rk1;
      if (ks < 2) {
        rq0 = -bf2f(qv[ks + 2][2 * jp]); rq1 = -bf2f(qv[ks + 2][2 * jp + 1]);
        rk0 = -bf2f(kv[ks + 2][2 * jp]); rk1 = -bf2f(kv[ks + 2][2 * jp + 1]);
      } else {
        rq0 = bf2f(qv[ks - 2][2 * jp]); rq1 = bf2f(qv[ks - 2][2 * jp + 1]);
        rk0 = bf2f(kv[ks - 2][2 * jp]); rk1 = bf2f(kv[ks - 2][2 * jp + 1]);
      }
      fq.u[jp] = pk2(q0 * c0 + rq0 * s0, q1 * c1 + rq1 * s1);
      fk.u[jp] = pk2(k0 * c0 + rk0 * s0, k1 * c1 + rk1 * s1);
    }
    qfr[ks] = fq.v; kfr[ks] = fk.v;
  }

  f32x16 accS;
#pragma unroll
  for (int i = 0; i < 16; ++i) accS[i] = 0.f;
#pragma unroll
  for (int ks = 0; ks < 4; ++ks)
    accS = __builtin_amdgcn_mfma_f32_32x32x16_bf16(kfr[ks], qfr[ks], accS, 0, 0, 0);

  float p[16];
  float mx = -1e30f;
#pragma unroll
  for (int r = 0; r < 16; ++r) { p[r] = accS[r] * 0.125f; mx = fmaxf(mx, p[r]); }
  mx = fmaxf(mx, __shfl_xor(mx, 32, 64));
  float sum = 0.f;
#pragma unroll
  for (int r = 0; r < 16; ++r) { p[r] = __expf(p[r] - mx); sum += p[r]; }
  sum += __shfl_xor(sum, 32, 64);
  const float inv = 1.f / sum;
#pragma unroll
  for (int r = 0; r < 16; ++r) p[r] *= inv;

  bf16x8 pfr[2];
  {
    FU f0, f1;
    unsigned a0 = hi ? pk2(p[0], p[1]) : pk2(p[4], p[5]);
    unsigned a1 = hi ? pk2(p[2], p[3]) : pk2(p[6], p[7]);
    unsigned b0 = (unsigned)__shfl_xor((int)a0, 32, 64);
    unsigned b1 = (unsigned)__shfl_xor((int)a1, 32, 64);
    if (hi) { f0.u[0] = b0; f0.u[1] = b1; f0.u[2] = pk2(p[4], p[5]); f0.u[3] = pk2(p[6], p[7]); }
    else    { f0.u[0] = pk2(p[0], p[1]); f0.u[1] = pk2(p[2], p[3]); f0.u[2] = b0; f0.u[3] = b1; }
    unsigned a2 = hi ? pk2(p[8], p[9])   : pk2(p[12], p[13]);
    unsigned a3 = hi ? pk2(p[10], p[11]) : pk2(p[14], p[15]);
    unsigned b2 = (unsigned)__shfl_xor((int)a2, 32, 64);
    unsigned b3 = (unsigned)__shfl_xor((int)a3, 32, 64);
    if (hi) { f1.u[0] = b2; f1.u[1] = b3; f1.u[2] = pk2(p[12], p[13]); f1.u[3] = pk2(p[14], p[15]); }
    else    { f1.u[0] = pk2(p[8], p[9]); f1.u[1] = pk2(p[10], p[11]); f1.u[2] = b2; f1.u[3] = b3; }
    pfr[0] = f0.v; pfr[1] = f1.v;
  }

  f32x16 accO[2];
#pragma unroll
  for (int i = 0; i < 16; ++i) { accO[0][i] = 0.f; accO[1][i] = 0.f; }
  const int dl = lane & 31;
#pragma unroll
  for (int dh = 0; dh < 2; ++dh) {
    int d = dh * 32 + dl;
    int sx = (d ^ (d >> 2)) & 3;
#pragma unroll
    for (int ks = 0; ks < 2; ++ks) {
      bf16x8 vf = *(const bf16x8*)&Vt[wv][d][(((2 * ks + hi) ^ sx) & 3) * 8];
      accO[dh] = __builtin_amdgcn_mfma_f32_32x32x16_bf16(pfr[ks], vf, accO[dh], 0, 0, 0);
    }
  }

#pragma unroll
  for (int r = 0; r < 16; ++r) {
    int n = (r & 3) + 8 * (r >> 2) + 4 * hi;
    size_t o = (size_t)(w * 32 + n) * 1024 + h * 64 + dl;
    aout[o] = f2bf(accO[0][r]);
    aout[o + 32] = f2bf(accO[1][r]);
  }
}

extern "C" void kernel_launch(void* const* d_in, const int* in_sizes, int n_in,
                              void* d_out, int out_size, void* d_ws, size_t ws_size,
                              hipStream_t stream) {
  const float* x     = (const float*)d_in[0];
  const float* w_qkv = (const float*)d_in[1];
  const float* w_out = (const float*)d_in[2];
  const float* gamma = (const float*)d_in[3];
  const float* beta  = (const float*)d_in[4];

  char* ws = (char*)d_ws;
  unsigned short* wqkv_bf = (unsigned short*)(ws);                       // 6,291,456 B
  unsigned short* wout_bf = (unsigned short*)(ws + 6291456);             // 2,097,152 B
  float* mu    = (float*)(ws + 8388608);                                 // 65,536 B
  float* rstd  = (float*)(ws + 8454144);                                 // 65,536 B
  float* ropeT = (float*)(ws + 8519680);                                 // 8,192 B
  unsigned short* normed = (unsigned short*)(ws + 8527872);              // 33,554,432 B
  unsigned short* qkv    = (unsigned short*)(ws + 42082304);             // 100,663,296 B
  unsigned short* aout   = normed;  // reuse: normed dead after GEMM1

  cvt_kernel<<<3072, 256, 0, stream>>>(w_qkv, wqkv_bf, 3072 * 1024 / 4);
  cvt_kernel<<<1024, 256, 0, stream>>>(w_out, wout_bf, 1024 * 1024 / 4);
  rope_tab_kernel<<<4, 256, 0, stream>>>(ropeT);
  ln_stats_kernel<<<256, 256, 0, stream>>>(x, mu, rstd);
  ln_tr_kernel<<<4096, 256, 0, stream>>>(x, mu, rstd, gamma, beta, normed);
  // GEMM1: 16384x3072x1024 -> grid 64*12 = 768 (3 rounds)
  gemm8p_kernel<0><<<768, 512, 0, stream>>>(normed, wqkv_bf, qkv, 3072, 12, 1024,
                                            nullptr, nullptr);
  attn_kernel<<<2048, 256, 0, stream>>>(qkv, ropeT, aout);
  // GEMM2: 16384x1024x1024 -> grid 64*4 = 256 (1 round), fused transpose+residual
  gemm8p_kernel<1><<<256, 512, 0, stream>>>(aout, wout_bf, nullptr, 0, 4, 1024,
                                            x, (float*)d_out);
}

// Round 5
// 218.776 us; speedup vs baseline: 1.6245x; 1.0072x over previous
//
#include <hip/hip_runtime.h>

#define T_TOK 16384
#define C_DIM 1024

typedef float f32x4 __attribute__((ext_vector_type(4)));
typedef float f32x16 __attribute__((ext_vector_type(16)));
typedef __bf16 bf16x8 __attribute__((ext_vector_type(8)));
typedef unsigned short u16x8 __attribute__((ext_vector_type(8)));
typedef unsigned short u16x4 __attribute__((ext_vector_type(4)));

__device__ __forceinline__ unsigned short f2bf(float f) {
  union { float f; unsigned u; } v; v.f = f;
  unsigned r = v.u + 0x7fffu + ((v.u >> 16) & 1u);
  return (unsigned short)(r >> 16);
}
__device__ __forceinline__ float bf2f(unsigned short h) {
  union { unsigned u; float f; } v; v.u = ((unsigned)h) << 16;
  return v.f;
}
__device__ __forceinline__ unsigned pk2(float a, float b) {
  return (unsigned)f2bf(a) | ((unsigned)f2bf(b) << 16);
}

// ---------------- f32 -> bf16 weight conversion ----------------
__global__ __launch_bounds__(256) void cvt_kernel(const float* __restrict__ in,
                                                  unsigned short* __restrict__ out, int n4) {
  int i = blockIdx.x * 256 + threadIdx.x;
  if (i >= n4) return;
  f32x4 v = *(const f32x4*)(in + (size_t)i * 4);
  u16x4 o;
#pragma unroll
  for (int j = 0; j < 4; ++j) o[j] = f2bf(v[j]);
  *(u16x4*)(out + (size_t)i * 4) = o;
}

// ---------------- RoPE table: [32 pos][32 dmod] float2 (cos,sin) ----------------
__global__ __launch_bounds__(256) void rope_tab_kernel(float* __restrict__ tab) {
  int idx = blockIdx.x * 256 + threadIdx.x;
  if (idx >= 1024) return;
  int mm = idx >> 5, d = idx & 31;
  float invf = powf(10000.f, -(float)d * (1.f / 32.f));
  float ang = (float)mm * invf;
  float s, c;
  sincosf(ang, &s, &c);
  tab[idx * 2] = c;
  tab[idx * 2 + 1] = s;
}

// ---------------- LayerNorm stats: mean/rstd per token ----------------
__global__ __launch_bounds__(256) void ln_stats_kernel(const float* __restrict__ x,
                                                       float* __restrict__ mu,
                                                       float* __restrict__ rstd) {
  __shared__ float s1[4][64];
  __shared__ float s2[4][64];
  const int tid = threadIdx.x;
  const int lt = tid & 63, cq = tid >> 6;
  const int t = blockIdx.x * 64 + lt;
  float s = 0.f, ss = 0.f;
  const float* p = x + (size_t)cq * 256 * T_TOK + t;
  for (int c = 0; c < 256; ++c) {
    float v = p[(size_t)c * T_TOK];
    s += v; ss += v * v;
  }
  s1[cq][lt] = s; s2[cq][lt] = ss;
  __syncthreads();
  if (tid < 64) {
    float S  = s1[0][tid] + s1[1][tid] + s1[2][tid] + s1[3][tid];
    float SS = s2[0][tid] + s2[1][tid] + s2[2][tid] + s2[3][tid];
    float m = S * (1.f / 1024.f);
    float var = SS * (1.f / 1024.f) - m * m;
    mu[blockIdx.x * 64 + tid] = m;
    rstd[blockIdx.x * 64 + tid] = rsqrtf(var + 1e-5f);
  }
}

// ---------------- LN apply + transpose: x (C,T) -> normed (T,C) bf16 ----------------
__global__ __launch_bounds__(256) void ln_tr_kernel(const float* __restrict__ x,
                                                    const float* __restrict__ mu,
                                                    const float* __restrict__ rstd,
                                                    const float* __restrict__ gamma,
                                                    const float* __restrict__ beta,
                                                    unsigned short* __restrict__ normed) {
  __shared__ float tile[64][65];
  __shared__ float gs[64], bs[64], ms[64], rs[64];
  const int tid = threadIdx.x;
  const int bt = blockIdx.x & 255;
  const int bc = blockIdx.x >> 8;
  const int t0 = bt * 64, c0 = bc * 64;
  if (tid < 64) {
    gs[tid] = gamma[c0 + tid];
    bs[tid] = beta[c0 + tid];
    ms[tid] = mu[t0 + tid];
    rs[tid] = rstd[t0 + tid];
  }
  const int lc = tid >> 4;
  const int lt4 = (tid & 15) * 4;
#pragma unroll
  for (int r = 0; r < 4; ++r) {
    int c = r * 16 + lc;
    f32x4 v = *(const f32x4*)&x[(size_t)(c0 + c) * T_TOK + t0 + lt4];
    tile[c][lt4 + 0] = v[0]; tile[c][lt4 + 1] = v[1];
    tile[c][lt4 + 2] = v[2]; tile[c][lt4 + 3] = v[3];
  }
  __syncthreads();
#pragma unroll
  for (int r = 0; r < 2; ++r) {
    int idx = r * 256 + tid;
    int t = idx >> 3;
    int c8 = (idx & 7) * 8;
    float m = ms[t], rr = rs[t];
    u16x8 o;
#pragma unroll
    for (int j = 0; j < 8; ++j) {
      float v = tile[c8 + j][t];
      v = (v - m) * rr * gs[c8 + j] + bs[c8 + j];
      o[j] = f2bf(v);
    }
    *(u16x8*)&normed[(size_t)(t0 + t) * C_DIM + c0 + c8] = o;
  }
}

#define GLDS(gp, lp) \
  __builtin_amdgcn_global_load_lds((const __attribute__((address_space(1))) void*)(gp), \
                                   (__attribute__((address_space(3))) void*)(lp), 16, 0, 0)

#define BAR() __builtin_amdgcn_s_barrier()
#define LGKM0() asm volatile("s_waitcnt lgkmcnt(0)" ::: "memory")

// ================= 256x256 pipelined 4-phase bf16 NT GEMM =================
// C = A * B^T, A: MxK row-major bf16, B: NxK row-major bf16.
// EPI 0: bf16 out (ld=ldo). EPI 1: f32 transposed out + residual.
// 512 threads = 8 waves (2M x 4N); per-wave C: 128x64; BK=64; LDS 128 KiB dbuf.
// Register-loads pipelined one phase ahead (drain under MFMA); stages for t+2
// issued at P2 (B) / P3 (A) into just-freed regions of the CURRENT buffer;
// vmcnt(8) once per K-tile gives every load 4-5 phases of flight.
template <int EPI>
__global__ __launch_bounds__(512, 2) void gemm8p_kernel(const unsigned short* __restrict__ A,
                                                        const unsigned short* __restrict__ B,
                                                        unsigned short* __restrict__ Obf,
                                                        int ldo, int nbn, int K,
                                                        const float* __restrict__ Xadd,
                                                        float* __restrict__ Ofp) {
  __shared__ unsigned short Lds[2][2][2][8192];  // [op A/B][buf][half][row*64+col]
  const int tid = threadIdx.x;
  const int w = tid >> 6, lane = tid & 63;
  const int wm = w >> 2, wn = w & 3;

  // XCD-banded, mt-fast block mapping (requires nbm % 8 == 0)
  const int nbm = gridDim.x / nbn;
  const int mtpx = nbm >> 3;
  const int xcd = blockIdx.x & 7;
  const int ib = blockIdx.x >> 3;
  const int mt = xcd * mtpx + (ib % mtpx);
  const int nt = ib / mtpx;
  const size_t m0 = (size_t)mt * 256, n0 = (size_t)nt * 256;

  // staging source base: row (lane>>3), pre-swizzled k-slot (lane&7)^(lane>>3)
  const unsigned short* gA = A + (m0 + (lane >> 3)) * (size_t)K + ((lane & 7) ^ (lane >> 3)) * 8;
  const unsigned short* gB = B + (n0 + (lane >> 3)) * (size_t)K + ((lane & 7) ^ (lane >> 3)) * 8;
  const int wrow = w * 8;

  auto stageA = [&](int b, int h, int kt) {
    const unsigned short* g = gA + (size_t)(h * 128) * K + (size_t)kt * 64;
    GLDS(g + (size_t)wrow * K,        &Lds[0][b][h][wrow * 64]);
    GLDS(g + (size_t)(64 + wrow) * K, &Lds[0][b][h][(64 + wrow) * 64]);
  };
  auto stageB = [&](int b, int h, int kt) {
    const unsigned short* g = gB + (size_t)(h * 128) * K + (size_t)kt * 64;
    GLDS(g + (size_t)wrow * K,        &Lds[1][b][h][wrow * 64]);
    GLDS(g + (size_t)(64 + wrow) * K, &Lds[1][b][h][(64 + wrow) * 64]);
  };

  f32x4 acc[8][4];
#pragma unroll
  for (int i = 0; i < 8; ++i)
#pragma unroll
    for (int j = 0; j < 4; ++j) acc[i][j] = (f32x4){0.f, 0.f, 0.f, 0.f};

  const int KT = K >> 6;
  const int off_r = (lane & 15) * 64;
  const int slot0 = (((lane >> 4) ^ (lane & 7)) * 8);
  const int slot1 = slot0 ^ 32;
  const int boff = (wn & 1) * 4096;

  bf16x8 aLo[4][2], aHi[4][2], bLo[2][2], bHi[2][2];

  // ---- prologue: stage tile0 + tile1 fully; wait tile0; read t0's aLo/bLo ----
  stageA(0, 0, 0); stageA(0, 1, 0); stageB(0, 0, 0); stageB(0, 1, 0);
  if (KT > 1) {
    stageB(1, 0, 1); stageB(1, 1, 1); stageA(1, 0, 1); stageA(1, 1, 1);
    asm volatile("s_waitcnt vmcnt(8)" ::: "memory");
  } else {
    asm volatile("s_waitcnt vmcnt(0)" ::: "memory");
  }
  BAR();
  {
    const unsigned short* Ab = &Lds[0][0][wm][0];
    const unsigned short* Bb = &Lds[1][0][wn >> 1][boff];
#pragma unroll
    for (int mi = 0; mi < 4; ++mi) {
      aLo[mi][0] = *(const bf16x8*)&Ab[mi * 1024 + off_r + slot0];
      aLo[mi][1] = *(const bf16x8*)&Ab[mi * 1024 + off_r + slot1];
    }
#pragma unroll
    for (int ni = 0; ni < 2; ++ni) {
      bLo[ni][0] = *(const bf16x8*)&Bb[ni * 1024 + off_r + slot0];
      bLo[ni][1] = *(const bf16x8*)&Bb[ni * 1024 + off_r + slot1];
    }
  }

  int bb = 0;
  for (int t = 0; t < KT; ++t, bb ^= 1) {
    const unsigned short* Ab = &Lds[0][bb][wm][0];
    const unsigned short* Bb = &Lds[1][bb][wn >> 1][boff];

    // ---- P0: drain aLo/bLo; issue bHi reads; MFMA q0 (aLo,bLo) ----
    LGKM0();
#pragma unroll
    for (int ni = 0; ni < 2; ++ni) {
      bHi[ni][0] = *(const bf16x8*)&Bb[(ni + 2) * 1024 + off_r + slot0];
      bHi[ni][1] = *(const bf16x8*)&Bb[(ni + 2) * 1024 + off_r + slot1];
    }
    __builtin_amdgcn_s_setprio(1);
#pragma unroll
    for (int mi = 0; mi < 4; ++mi)
#pragma unroll
      for (int ni = 0; ni < 2; ++ni)
#pragma unroll
        for (int ks = 0; ks < 2; ++ks)
          acc[mi][ni] = __builtin_amdgcn_mfma_f32_16x16x32_bf16(aLo[mi][ks], bLo[ni][ks], acc[mi][ni], 0, 0, 0);
    __builtin_amdgcn_s_setprio(0);
    BAR();

    // ---- P1: drain bHi; issue aHi reads; MFMA q1 (aLo,bHi) ----
    LGKM0();
#pragma unroll
    for (int mi = 0; mi < 4; ++mi) {
      aHi[mi][0] = *(const bf16x8*)&Ab[(mi + 4) * 1024 + off_r + slot0];
      aHi[mi][1] = *(const bf16x8*)&Ab[(mi + 4) * 1024 + off_r + slot1];
    }
    __builtin_amdgcn_s_setprio(1);
#pragma unroll
    for (int mi = 0; mi < 4; ++mi)
#pragma unroll
      for (int ni = 0; ni < 2; ++ni)
#pragma unroll
        for (int ks = 0; ks < 2; ++ks)
          acc[mi][ni + 2] = __builtin_amdgcn_mfma_f32_16x16x32_bf16(aLo[mi][ks], bHi[ni][ks], acc[mi][ni + 2], 0, 0, 0);
    __builtin_amdgcn_s_setprio(0);
    BAR();

    // ---- P2: drain aHi; stage B(t+2) into current buf (B dead after P1-end BAR);
    //          MFMA q2 (aHi,bHi) ----
    LGKM0();
    if (t + 2 < KT) { stageB(bb, 0, t + 2); stageB(bb, 1, t + 2); }
    __builtin_amdgcn_s_setprio(1);
#pragma unroll
    for (int mi = 0; mi < 4; ++mi)
#pragma unroll
      for (int ni = 0; ni < 2; ++ni)
#pragma unroll
        for (int ks = 0; ks < 2; ++ks)
          acc[mi + 4][ni + 2] = __builtin_amdgcn_mfma_f32_16x16x32_bf16(aHi[mi][ks], bHi[ni][ks], acc[mi + 4][ni + 2], 0, 0, 0);
    __builtin_amdgcn_s_setprio(0);
    BAR();

    // ---- P3: stage A(t+2) (A dead after P2-end BAR); vmcnt gate for t+1;
    //          MFMA q3 (aHi,bLo); then read t+1's aLo/bLo ----
    if (t + 2 < KT) { stageA(bb, 0, t + 2); stageA(bb, 1, t + 2); }
    if (t + 1 < KT) {
      if (t + 2 < KT) {
        asm volatile("s_waitcnt vmcnt(8)" ::: "memory");
      } else {
        asm volatile("s_waitcnt vmcnt(0)" ::: "memory");
      }
      BAR();  // all waves: tile t+1 fully landed; safe to read buf bb^1
    }
    __builtin_amdgcn_s_setprio(1);
#pragma unroll
    for (int mi = 0; mi < 4; ++mi)
#pragma unroll
      for (int ni = 0; ni < 2; ++ni)
#pragma unroll
        for (int ks = 0; ks < 2; ++ks)
          acc[mi + 4][ni] = __builtin_amdgcn_mfma_f32_16x16x32_bf16(aHi[mi][ks], bLo[ni][ks], acc[mi + 4][ni], 0, 0, 0);
    __builtin_amdgcn_s_setprio(0);
    if (t + 1 < KT) {
      const unsigned short* Ab2 = &Lds[0][bb ^ 1][wm][0];
      const unsigned short* Bb2 = &Lds[1][bb ^ 1][wn >> 1][boff];
#pragma unroll
      for (int mi = 0; mi < 4; ++mi) {
        aLo[mi][0] = *(const bf16x8*)&Ab2[mi * 1024 + off_r + slot0];
        aLo[mi][1] = *(const bf16x8*)&Ab2[mi * 1024 + off_r + slot1];
      }
#pragma unroll
      for (int ni = 0; ni < 2; ++ni) {
        bLo[ni][0] = *(const bf16x8*)&Bb2[ni * 1024 + off_r + slot0];
        bLo[ni][1] = *(const bf16x8*)&Bb2[ni * 1024 + off_r + slot1];
      }
    }
    // no barrier here: P0's LGKM0 + the P3 vmcnt-BAR provide all guarantees
  }

  if (EPI == 0) {
    // wave-private LDS repack -> coalesced u16x8 stores (LDS fully dead post-loop)
    unsigned short* cw = &Lds[0][0][0][0] + (size_t)w * 8192;
#pragma unroll
    for (int mi = 0; mi < 8; ++mi)
#pragma unroll
      for (int ni = 0; ni < 4; ++ni)
#pragma unroll
        for (int r = 0; r < 4; ++r)
          cw[(mi * 16 + (lane >> 4) * 4 + r) * 64 + ni * 16 + (lane & 15)] = f2bf(acc[mi][ni][r]);
    LGKM0();
    const size_t gr0 = m0 + wm * 128;
    const size_t gc0 = n0 + wn * 64;
#pragma unroll
    for (int it = 0; it < 16; ++it) {
      int idx = it * 64 + lane;
      int rr = idx >> 3, c8 = (idx & 7) * 8;
      *(u16x8*)&Obf[(gr0 + rr) * (size_t)ldo + gc0 + c8] = *(const u16x8*)&cw[rr * 64 + c8];
    }
  } else {
    const size_t gr0 = m0 + wm * 128 + (lane >> 4) * 4;
    const size_t gc0 = n0 + wn * 64 + (lane & 15);
#pragma unroll
    for (int mi = 0; mi < 8; ++mi) {
      size_t row = gr0 + mi * 16;
#pragma unroll
      for (int ni = 0; ni < 4; ++ni) {
        size_t col = gc0 + ni * 16;
        f32x4 xv = *(const f32x4*)&Xadd[col * T_TOK + row];
        f32x4 o = acc[mi][ni] + xv;
        *(f32x4*)&Ofp[col * T_TOK + row] = o;
      }
    }
  }
}

// ---------------- MFMA windowed attention with RoPE ----------------
__global__ __launch_bounds__(256) void attn_kernel(const unsigned short* __restrict__ qkv,
                                                   const float* __restrict__ ropeT,
                                                   unsigned short* __restrict__ aout) {
  __shared__ unsigned short Vt[4][64][32];
  const int tid = threadIdx.x;
  const int wv = tid >> 6;
  const int lane = tid & 63;
  const int m = lane & 31;
  const int hi = lane >> 5;
  const int gw = blockIdx.x * 4 + wv;
  const int w = gw >> 4, h = gw & 15;
  const size_t rowbase = ((size_t)(w * 32 + m)) * 3072 + (size_t)h * 64;
  const unsigned short* qp = qkv + rowbase;

  u16x8 qv[4], kv[4], vv[4];
#pragma unroll
  for (int s = 0; s < 4; ++s) {
    int off = s * 16 + hi * 8;
    qv[s] = *(const u16x8*)(qp + off);
    kv[s] = *(const u16x8*)(qp + 1024 + off);
    vv[s] = *(const u16x8*)(qp + 2048 + off);
  }

#pragma unroll
  for (int s = 0; s < 4; ++s)
#pragma unroll
    for (int j = 0; j < 8; ++j) {
      int d = s * 16 + hi * 8 + j;
      int slot = (((m >> 3) ^ (d ^ (d >> 2))) & 3) * 8 + (m & 7);
      Vt[wv][d][slot] = vv[s][j];
    }

  f32x4 ct[2][4];
  const float* tp = ropeT + (size_t)(m * 32 + hi * 8) * 2;
#pragma unroll
  for (int kp = 0; kp < 2; ++kp)
#pragma unroll
    for (int q = 0; q < 4; ++q)
      ct[kp][q] = *(const f32x4*)(tp + kp * 32 + q * 4);

  union FU { unsigned u[4]; bf16x8 v; };
  bf16x8 qfr[4], kfr[4];
#pragma unroll
  for (int ks = 0; ks < 4; ++ks) {
    const int kp = ks & 1;
    FU fq, fk;
#pragma unroll
    for (int jp = 0; jp < 4; ++jp) {
      float c0 = ct[kp][jp][0], s0 = ct[kp][jp][1];
      float c1 = ct[kp][jp][2], s1 = ct[kp][jp][3];
      float q0 = bf2f(qv[ks][2 * jp]), q1 = bf2f(qv[ks][2 * jp + 1]);
      float k0 = bf2f(kv[ks][2 * jp]), k1 = bf2f(kv[ks][2 * jp + 1]);
      float rq0, rq1, rk0, rk1;
      if (ks < 2) {
        rq0 = -bf2f(qv[ks + 2][2 * jp]); rq1 = -bf2f(qv[ks + 2][2 * jp + 1]);
        rk0 = -bf2f(kv[ks + 2][2 * jp]); rk1 = -bf2f(kv[ks + 2][2 * jp + 1]);
      } else {
        rq0 = bf2f(qv[ks - 2][2 * jp]); rq1 = bf2f(qv[ks - 2][2 * jp + 1]);
        rk0 = bf2f(kv[ks - 2][2 * jp]); rk1 = bf2f(kv[ks - 2][2 * jp + 1]);
      }
      fq.u[jp] = pk2(q0 * c0 + rq0 * s0, q1 * c1 + rq1 * s1);
      fk.u[jp] = pk2(k0 * c0 + rk0 * s0, k1 * c1 + rk1 * s1);
    }
    qfr[ks] = fq.v; kfr[ks] = fk.v;
  }

  f32x16 accS;
#pragma unroll
  for (int i = 0; i < 16; ++i) accS[i] = 0.f;
#pragma unroll
  for (int ks = 0; ks < 4; ++ks)
    accS = __builtin_amdgcn_mfma_f32_32x32x16_bf16(kfr[ks], qfr[ks], accS, 0, 0, 0);

  float p[16];
  float mx = -1e30f;
#pragma unroll
  for (int r = 0; r < 16; ++r) { p[r] = accS[r] * 0.125f; mx = fmaxf(mx, p[r]); }
  mx = fmaxf(mx, __shfl_xor(mx, 32, 64));
  float sum = 0.f;
#pragma unroll
  for (int r = 0; r < 16; ++r) { p[r] = __expf(p[r] - mx); sum += p[r]; }
  sum += __shfl_xor(sum, 32, 64);
  const float inv = 1.f / sum;
#pragma unroll
  for (int r = 0; r < 16; ++r) p[r] *= inv;

  bf16x8 pfr[2];
  {
    FU f0, f1;
    unsigned a0 = hi ? pk2(p[0], p[1]) : pk2(p[4], p[5]);
    unsigned a1 = hi ? pk2(p[2], p[3]) : pk2(p[6], p[7]);
    unsigned b0 = (unsigned)__shfl_xor((int)a0, 32, 64);
    unsigned b1 = (unsigned)__shfl_xor((int)a1, 32, 64);
    if (hi) { f0.u[0] = b0; f0.u[1] = b1; f0.u[2] = pk2(p[4], p[5]); f0.u[3] = pk2(p[6], p[7]); }
    else    { f0.u[0] = pk2(p[0], p[1]); f0.u[1] = pk2(p[2], p[3]); f0.u[2] = b0; f0.u[3] = b1; }
    unsigned a2 = hi ? pk2(p[8], p[9])   : pk2(p[12], p[13]);
    unsigned a3 = hi ? pk2(p[10], p[11]) : pk2(p[14], p[15]);
    unsigned b2 = (unsigned)__shfl_xor((int)a2, 32, 64);
    unsigned b3 = (unsigned)__shfl_xor((int)a3, 32, 64);
    if (hi) { f1.u[0] = b2; f1.u[1] = b3; f1.u[2] = pk2(p[12], p[13]); f1.u[3] = pk2(p[14], p[15]); }
    else    { f1.u[0] = pk2(p[8], p[9]); f1.u[1] = pk2(p[10], p[11]); f1.u[2] = b2; f1.u[3] = b3; }
    pfr[0] = f0.v; pfr[1] = f1.v;
  }

  f32x16 accO[2];
#pragma unroll
  for (int i = 0; i < 16; ++i) { accO[0][i] = 0.f; accO[1][i] = 0.f; }
  const int dl = lane & 31;
#pragma unroll
  for (int dh = 0; dh < 2; ++dh) {
    int d = dh * 32 + dl;
    int sx = (d ^ (d >> 2)) & 3;
#pragma unroll
    for (int ks = 0; ks < 2; ++ks) {
      bf16x8 vf = *(const bf16x8*)&Vt[wv][d][(((2 * ks + hi) ^ sx) & 3) * 8];
      accO[dh] = __builtin_amdgcn_mfma_f32_32x32x16_bf16(pfr[ks], vf, accO[dh], 0, 0, 0);
    }
  }

#pragma unroll
  for (int r = 0; r < 16; ++r) {
    int n = (r & 3) + 8 * (r >> 2) + 4 * hi;
    size_t o = (size_t)(w * 32 + n) * 1024 + h * 64 + dl;
    aout[o] = f2bf(accO[0][r]);
    aout[o + 32] = f2bf(accO[1][r]);
  }
}

extern "C" void kernel_launch(void* const* d_in, const int* in_sizes, int n_in,
                              void* d_out, int out_size, void* d_ws, size_t ws_size,
                              hipStream_t stream) {
  const float* x     = (const float*)d_in[0];
  const float* w_qkv = (const float*)d_in[1];
  const float* w_out = (const float*)d_in[2];
  const float* gamma = (const float*)d_in[3];
  const float* beta  = (const float*)d_in[4];

  char* ws = (char*)d_ws;
  unsigned short* wqkv_bf = (unsigned short*)(ws);                       // 6,291,456 B
  unsigned short* wout_bf = (unsigned short*)(ws + 6291456);             // 2,097,152 B
  float* mu    = (float*)(ws + 8388608);                                 // 65,536 B
  float* rstd  = (float*)(ws + 8454144);                                 // 65,536 B
  float* ropeT = (float*)(ws + 8519680);                                 // 8,192 B
  unsigned short* normed = (unsigned short*)(ws + 8527872);              // 33,554,432 B
  unsigned short* qkv    = (unsigned short*)(ws + 42082304);             // 100,663,296 B
  unsigned short* aout   = normed;  // reuse: normed dead after GEMM1

  cvt_kernel<<<3072, 256, 0, stream>>>(w_qkv, wqkv_bf, 3072 * 1024 / 4);
  cvt_kernel<<<1024, 256, 0, stream>>>(w_out, wout_bf, 1024 * 1024 / 4);
  rope_tab_kernel<<<4, 256, 0, stream>>>(ropeT);
  ln_stats_kernel<<<256, 256, 0, stream>>>(x, mu, rstd);
  ln_tr_kernel<<<4096, 256, 0, stream>>>(x, mu, rstd, gamma, beta, normed);
  // GEMM1: 16384x3072x1024 -> grid 64*12 = 768 (3 rounds)
  gemm8p_kernel<0><<<768, 512, 0, stream>>>(normed, wqkv_bf, qkv, 3072, 12, 1024,
                                            nullptr, nullptr);
  attn_kernel<<<2048, 256, 0, stream>>>(qkv, ropeT, aout);
  // GEMM2: 16384x1024x1024 -> grid 64*4 = 256 (1 round), fused transpose+residual
  gemm8p_kernel<1><<<256, 512, 0, stream>>>(aout, wout_bf, nullptr, 0, 4, 1024,
                                            x, (float*)d_out);
}